// Round 7
// baseline (345.097 us; speedup 1.0000x reference)
//
#include <hip/hip_runtime.h>
#include <hip/hip_bf16.h>
#include <math.h>

#define BN 4
#define HIq 128
#define WIq 128
#define DIM 128
#define HOq 64
#define WOq 64
#define NPOS 4096      // HO*WO
#define NTOK 16384     // HI*WI
#define EPS_LN 1e-5f
#define EPS_A 1e-6f

typedef __attribute__((ext_vector_type(8))) short bf16x8;
typedef __attribute__((ext_vector_type(4))) float f32x4;

__device__ __forceinline__ unsigned short f2bf(float f) {
    unsigned int u = __float_as_uint(f);
    u = (u + 0x7FFFu + ((u >> 16) & 1u)) >> 16;
    return (unsigned short)u;
}

__device__ __forceinline__ float bf2f(unsigned short u) {
    return __uint_as_float((unsigned int)u << 16);
}

__device__ __forceinline__ int nb_index(int h, int w, int t) {
    int ch = min(max(h, 1), HOq - 2);
    int cw = min(max(w, 1), WOq - 2);
    int dr = t / 3 - 1, dc = t % 3 - 1;
    return (ch + dr) * WOq + (cw + dc);
}

// ---------------------------------------------------------------------------
// x -> bf16, LN(x) -> bf16. Wave wv handles row blockIdx*4+wv.
// v7: float2 loads, packed 2xbf16 stores.
__global__ void prep_ln_kernel(const float* __restrict__ x,
                               const float* __restrict__ g,
                               const float* __restrict__ bb,
                               unsigned short* __restrict__ x_bf,
                               unsigned short* __restrict__ xln_bf) {
    int tid = threadIdx.x, wv = tid >> 6, lane = tid & 63;
    long row = (long)blockIdx.x * 4 + wv;
    const float2* xr = (const float2*)(x + row * DIM);
    float2 v = xr[lane];
    float s = v.x + v.y, ss = v.x * v.x + v.y * v.y;
    #pragma unroll
    for (int off = 32; off; off >>= 1) {
        s  += __shfl_xor(s, off, 64);
        ss += __shfl_xor(ss, off, 64);
    }
    float mu = s * (1.0f / DIM);
    float var = fmaxf(ss * (1.0f / DIM) - mu * mu, 0.0f);
    float rstd = rsqrtf(var + EPS_LN);
    float2 gg = ((const float2*)g)[lane];
    float2 bv = ((const float2*)bb)[lane];
    unsigned int xo = (unsigned int)f2bf(v.x) | ((unsigned int)f2bf(v.y) << 16);
    *(unsigned int*)&x_bf[row * DIM + 2 * lane] = xo;
    unsigned int lo = (unsigned int)f2bf((v.x - mu) * rstd * gg.x + bv.x)
                    | ((unsigned int)f2bf((v.y - mu) * rstd * gg.y + bv.y) << 16);
    *(unsigned int*)&xln_bf[row * DIM + 2 * lane] = lo;
}

// ---------------------------------------------------------------------------
// conv_w [O][I][3][3] -> wt [o][tap*128+i] bf16
__global__ void conv_wt_kernel(const float* __restrict__ cw, unsigned short* __restrict__ wt) {
    int o = blockIdx.x, tap = blockIdx.y, i = threadIdx.x;
    wt[(long)o * 1152 + tap * 128 + i] = f2bf(cw[((long)o * 128 + i) * 9 + tap]);
}

// k_w/v_w/q_w [i][o] -> [o][i] bf16 ; mlp_w1 [i][j](128x256) -> [j][i] ;
// mlp_w2 [j][o](256x128) -> [o][j]
__global__ void wt_all_kernel(const float* __restrict__ kw, const float* __restrict__ vw,
                              const float* __restrict__ qw,
                              const float* __restrict__ w1, const float* __restrict__ w2,
                              unsigned short* __restrict__ kwt, unsigned short* __restrict__ vwt,
                              unsigned short* __restrict__ qwt,
                              unsigned short* __restrict__ w1t, unsigned short* __restrict__ w2t) {
    int o = blockIdx.x, i = threadIdx.x;   // 128 x 128
    kwt[o * DIM + i] = f2bf(kw[i * DIM + o]);
    vwt[o * DIM + i] = f2bf(vw[i * DIM + o]);
    qwt[o * DIM + i] = f2bf(qw[i * DIM + o]);
    // w1: [i=128][j=256] -> w1t[j=256][i=128]
    w1t[(2 * o) * DIM + i]     = f2bf(w1[i * 256 + 2 * o]);
    w1t[(2 * o + 1) * DIM + i] = f2bf(w1[i * 256 + 2 * o + 1]);
    // w2: [j=256][o=128] -> w2t[o=128][j=256]
    w2t[o * 256 + i]       = f2bf(w2[i * DIM + o]);
    w2t[o * 256 + 128 + i] = f2bf(w2[(128 + i) * DIM + o]);
}

// ---------------------------------------------------------------------------
// Conv as implicit-im2col MFMA GEMM with fused LN epilogue.
// Full-row LDS staging per tap -> 18 barriers/block; inner loop pure LDS+MFMA.
__global__ __launch_bounds__(256) void conv_mfma_kernel(
        const unsigned short* __restrict__ x_bf,
        const unsigned short* __restrict__ wt,
        const float* __restrict__ ln_g, const float* __restrict__ ln_b,
        float* __restrict__ out_x) {
    __shared__ __align__(16) char smem[52224];
    unsigned short (*As)[136] = (unsigned short(*)[136])smem;            // 17408 B
    unsigned short (*Bs)[136] = (unsigned short(*)[136])(smem + 17408);  // 34816 B
    float (*o_s)[132]         = (float(*)[132])smem;                     // aliased, 33792 B

    int tid = threadIdx.x;
    int wv = tid >> 6, lane = tid & 63;
    int quad = lane >> 4, l15 = lane & 15;
    int wr = wv >> 1, wc = wv & 1;
    int b = blockIdx.x >> 6, ho = blockIdx.x & 63;

    f32x4 acc[2][4];
    #pragma unroll
    for (int mt = 0; mt < 2; ++mt)
        #pragma unroll
        for (int nt = 0; nt < 4; ++nt) acc[mt][nt] = (f32x4){0.f, 0.f, 0.f, 0.f};

    for (int tap = 0; tap < 9; ++tap) {
        int kh = tap / 3, kw = tap % 3;
        int hi = 2 * ho - 1 + kh;
        bool hok = (hi >= 0) && (hi < HIq);
        __syncthreads();
        // stage A: 64 rows x 16 int4-chunks (full 128 channels)
        #pragma unroll
        for (int it = 0; it < 4; ++it) {
            int c = it * 256 + tid;
            int row = c >> 4, sg = c & 15;
            int wi = 2 * row - 1 + kw;
            int4 av = {0, 0, 0, 0};
            if (hok && wi >= 0 && wi < WIq)
                av = *(const int4*)(x_bf + (((long)b * HIq + hi) * WIq + wi) * DIM + sg * 8);
            *(int4*)&As[row][sg * 8] = av;
        }
        // stage B: 128 rows x 16 chunks
        #pragma unroll
        for (int it = 0; it < 8; ++it) {
            int c = it * 256 + tid;
            int row = c >> 4, sg = c & 15;
            *(int4*)&Bs[row][sg * 8] =
                *(const int4*)(wt + (long)row * 1152 + tap * 128 + sg * 8);
        }
        __syncthreads();
        #pragma unroll
        for (int ib = 0; ib < 4; ++ib) {
            bf16x8 afr[2], bfr[4];
            #pragma unroll
            for (int mt = 0; mt < 2; ++mt)
                afr[mt] = *(bf16x8*)&As[wr * 32 + mt * 16 + l15][ib * 32 + quad * 8];
            #pragma unroll
            for (int nt = 0; nt < 4; ++nt)
                bfr[nt] = *(bf16x8*)&Bs[wc * 64 + nt * 16 + l15][ib * 32 + quad * 8];
            #pragma unroll
            for (int mt = 0; mt < 2; ++mt)
                #pragma unroll
                for (int nt = 0; nt < 4; ++nt)
                    acc[mt][nt] = __builtin_amdgcn_mfma_f32_16x16x32_bf16(
                        afr[mt], bfr[nt], acc[mt][nt], 0, 0, 0);
        }
    }
    __syncthreads();   // As/Bs dead; o_s aliases them
    #pragma unroll
    for (int mt = 0; mt < 2; ++mt)
        #pragma unroll
        for (int r = 0; r < 4; ++r) {
            int wo = wr * 32 + mt * 16 + quad * 4 + r;
            #pragma unroll
            for (int nt = 0; nt < 4; ++nt) {
                int col = wc * 64 + nt * 16 + l15;
                o_s[wo][col] = acc[mt][nt][r];
            }
        }
    __syncthreads();

    // LN over channels per position; 4 threads per row, 32 cols each.
    {
        int r = tid >> 2, qq = tid & 3;
        float s = 0.f, ss = 0.f;
        #pragma unroll
        for (int j = 0; j < 32; ++j) {
            float v = o_s[r][qq * 32 + j];
            s += v; ss += v * v;
        }
        s  += __shfl_xor(s, 1, 64);  ss += __shfl_xor(ss, 1, 64);
        s  += __shfl_xor(s, 2, 64);  ss += __shfl_xor(ss, 2, 64);
        float mu = s * (1.0f / DIM);
        float var = fmaxf(ss * (1.0f / DIM) - mu * mu, 0.0f);
        float rstd = rsqrtf(var + EPS_LN);
        long outb = ((long)b * NPOS + ho * WOq) * DIM;
        float* xr = out_x + outb + (long)r * DIM + qq * 32;
        #pragma unroll
        for (int j = 0; j < 32; ++j) {
            int c = qq * 32 + j;
            xr[j] = (o_s[r][c] - mu) * rstd * ln_g[c] + ln_b[c];
        }
    }
}

// ---------------------------------------------------------------------------
// kv dual MFMA GEMM. K and V both written as bf16.
__global__ __launch_bounds__(256) void kv_mfma_kernel(
        const unsigned short* __restrict__ x_bf,
        const unsigned short* __restrict__ xln_bf,
        const unsigned short* __restrict__ kwt,
        const unsigned short* __restrict__ vwt,
        unsigned short* __restrict__ k_bf, unsigned short* __restrict__ v_bf) {
    __shared__ unsigned short Ak[64][40], Av[64][40];
    __shared__ unsigned short Bk[128][40], Bv[128][40];
    int tid = threadIdx.x;
    int wv = tid >> 6, lane = tid & 63;
    int quad = lane >> 4, l15 = lane & 15;
    int wr = wv >> 1, wc = wv & 1;
    long tokBase = (long)blockIdx.x * 64;

    f32x4 acck[2][4], accv[2][4];
    #pragma unroll
    for (int mt = 0; mt < 2; ++mt)
        #pragma unroll
        for (int nt = 0; nt < 4; ++nt) {
            acck[mt][nt] = (f32x4){0.f, 0.f, 0.f, 0.f};
            accv[mt][nt] = (f32x4){0.f, 0.f, 0.f, 0.f};
        }

    int m = tid >> 2, seg = tid & 3;
    #pragma unroll
    for (int ib = 0; ib < 4; ++ib) {
        __syncthreads();
        *(int4*)&Ak[m][seg * 8] = *(const int4*)(xln_bf + (tokBase + m) * DIM + ib * 32 + seg * 8);
        *(int4*)&Av[m][seg * 8] = *(const int4*)(x_bf   + (tokBase + m) * DIM + ib * 32 + seg * 8);
        #pragma unroll
        for (int r2 = 0; r2 < 2; ++r2) {
            int lin = r2 * 256 + tid;
            int n = lin >> 2, sg = lin & 3;
            *(int4*)&Bk[n][sg * 8] = *(const int4*)(kwt + (long)n * DIM + ib * 32 + sg * 8);
            *(int4*)&Bv[n][sg * 8] = *(const int4*)(vwt + (long)n * DIM + ib * 32 + sg * 8);
        }
        __syncthreads();
        bf16x8 ak[2], av2[2], bk[4], bv[4];
        #pragma unroll
        for (int mt = 0; mt < 2; ++mt) {
            ak[mt]  = *(bf16x8*)&Ak[wr * 32 + mt * 16 + l15][quad * 8];
            av2[mt] = *(bf16x8*)&Av[wr * 32 + mt * 16 + l15][quad * 8];
        }
        #pragma unroll
        for (int nt = 0; nt < 4; ++nt) {
            bk[nt] = *(bf16x8*)&Bk[wc * 64 + nt * 16 + l15][quad * 8];
            bv[nt] = *(bf16x8*)&Bv[wc * 64 + nt * 16 + l15][quad * 8];
        }
        #pragma unroll
        for (int mt = 0; mt < 2; ++mt)
            #pragma unroll
            for (int nt = 0; nt < 4; ++nt) {
                acck[mt][nt] = __builtin_amdgcn_mfma_f32_16x16x32_bf16(ak[mt],  bk[nt], acck[mt][nt], 0, 0, 0);
                accv[mt][nt] = __builtin_amdgcn_mfma_f32_16x16x32_bf16(av2[mt], bv[nt], accv[mt][nt], 0, 0, 0);
            }
    }
    #pragma unroll
    for (int mt = 0; mt < 2; ++mt)
        #pragma unroll
        for (int r = 0; r < 4; ++r) {
            long tok = tokBase + wr * 32 + mt * 16 + quad * 4 + r;
            int b = (int)(tok >> 14);
            int pix = (int)(tok & 16383);
            int ih = pix >> 7, iw = pix & 127;
            int g = (ih & 1) * 2 + (iw & 1);
            int pos = (ih >> 1) * WOq + (iw >> 1);
            long base = ((long)(b * 4 + g) * NPOS + pos) * DIM;
            #pragma unroll
            for (int nt = 0; nt < 4; ++nt) {
                int col = wc * 64 + nt * 16 + l15;
                k_bf[base + col] = f2bf(acck[mt][nt][r]);
                v_bf[base + col] = f2bf(accv[mt][nt][r]);
            }
        }
}

// ---------------------------------------------------------------------------
// q = LN(x_out)@q_w via MFMA, output bf16 (only attn reads q).
__global__ __launch_bounds__(256) void q_mfma_kernel(
        const float* __restrict__ x_out,
        const unsigned short* __restrict__ qwt,
        const float* __restrict__ ln_g, const float* __restrict__ ln_b,
        unsigned short* __restrict__ q) {
    __shared__ unsigned short sxbf[64][136];
    int tid = threadIdx.x;
    long base = (long)blockIdx.x * 64;

    // stage: LN(x_out) -> bf16. 4 threads per row; thread covers 32 cols.
    {
        int r = tid >> 2, qq = tid & 3;
        const float* xr = x_out + (base + r) * DIM + qq * 32;
        float vv[32];
        float s = 0.f, ss = 0.f;
        #pragma unroll
        for (int j = 0; j < 8; ++j) {
            float4 v4 = *(const float4*)(xr + j * 4);
            vv[j * 4 + 0] = v4.x; vv[j * 4 + 1] = v4.y;
            vv[j * 4 + 2] = v4.z; vv[j * 4 + 3] = v4.w;
            s += v4.x + v4.y + v4.z + v4.w;
            ss += v4.x * v4.x + v4.y * v4.y + v4.z * v4.z + v4.w * v4.w;
        }
        s  += __shfl_xor(s, 1, 64);  ss += __shfl_xor(ss, 1, 64);
        s  += __shfl_xor(s, 2, 64);  ss += __shfl_xor(ss, 2, 64);
        float mu = s * (1.0f / DIM);
        float var = fmaxf(ss * (1.0f / DIM) - mu * mu, 0.0f);
        float rstd = rsqrtf(var + EPS_LN);
        #pragma unroll
        for (int j = 0; j < 32; ++j) {
            int c = qq * 32 + j;
            sxbf[r][c] = f2bf((vv[j] - mu) * rstd * ln_g[c] + ln_b[c]);
        }
    }
    __syncthreads();

    int wv = tid >> 6, lane = tid & 63;
    int quad = lane >> 4, l15 = lane & 15;
    f32x4 acc[4][2];
    #pragma unroll
    for (int mt = 0; mt < 4; ++mt)
        #pragma unroll
        for (int nt = 0; nt < 2; ++nt) acc[mt][nt] = (f32x4){0.f, 0.f, 0.f, 0.f};

    #pragma unroll
    for (int kb = 0; kb < 4; ++kb) {
        bf16x8 afr[4], bfr[2];
        #pragma unroll
        for (int mt = 0; mt < 4; ++mt)
            afr[mt] = *(bf16x8*)&sxbf[mt * 16 + l15][kb * 32 + quad * 8];
        #pragma unroll
        for (int nt = 0; nt < 2; ++nt) {
            int n = wv * 32 + nt * 16 + l15;
            bfr[nt] = *(const bf16x8*)(qwt + (long)n * DIM + kb * 32 + quad * 8);
        }
        #pragma unroll
        for (int mt = 0; mt < 4; ++mt)
            #pragma unroll
            for (int nt = 0; nt < 2; ++nt)
                acc[mt][nt] = __builtin_amdgcn_mfma_f32_16x16x32_bf16(
                    afr[mt], bfr[nt], acc[mt][nt], 0, 0, 0);
    }
    #pragma unroll
    for (int mt = 0; mt < 4; ++mt)
        #pragma unroll
        for (int r = 0; r < 4; ++r) {
            long tok = base + mt * 16 + quad * 4 + r;
            #pragma unroll
            for (int nt = 0; nt < 2; ++nt) {
                int col = wv * 32 + nt * 16 + l15;
                q[tok * DIM + col] = f2bf(acc[mt][nt][r]);
            }
        }
}

// ---------------------------------------------------------------------------
__global__ void zero_kernel(float* __restrict__ p, int n) {
    int i = blockIdx.x * blockDim.x + threadIdx.x;
    if (i < n) p[i] = 0.0f;
}

// ---------------------------------------------------------------------------
// attn v7 (MFMA): as v6 + XCD-bijective block swizzle (1024 wg, 128/XCD:
// consecutive h-rows and g-pairs share Q strips -> L2 hits).
__global__ __launch_bounds__(256) void attn_mfma_kernel(
        const unsigned short* __restrict__ k_bf,
        const unsigned short* __restrict__ q_bf,
        const float* __restrict__ rpb,
        const float* __restrict__ tau,
        float* __restrict__ attn_out,
        float* __restrict__ col_sums) {
    __shared__ __align__(16) char smem[69632];
    __shared__ float colacc[192];
    unsigned short (*Ks)[136] = (unsigned short(*)[136])smem;            // 17408 B
    unsigned short (*Qs)[136] = (unsigned short(*)[136])(smem + 17408);  // 52224 B
    float (*S)[193]           = (float(*)[193])smem;                     // 49408 B aliased

    int tid = threadIdx.x;
    int bid = blockIdx.x;
    bid = (bid & 7) * 128 + (bid >> 3);   // bijective XCD swizzle (1024 % 8 == 0)
    int h = bid & 63, g = (bid >> 6) & 3, b = bid >> 8;
    int r0 = min(max(h, 1), HOq - 2) - 1;   // first Q strip row

    long kbase = ((long)(b * 4 + g) * NPOS + h * 64) * DIM;
    long qbase = ((long)b * NPOS + r0 * 64) * DIM;

    if (tid < 192) colacc[tid] = 0.f;

    // stage K (64 rows x 16 chunks) + Q (192 rows x 16 chunks), int4-vectorized
    #pragma unroll
    for (int it = 0; it < 4; ++it) {
        int lin = it * 256 + tid;          // 0..1023
        int row = lin >> 4, sg = lin & 15;
        *(int4*)&Ks[row][sg * 8] = *(const int4*)(k_bf + kbase + (long)row * DIM + sg * 8);
    }
    #pragma unroll
    for (int it = 0; it < 12; ++it) {
        int lin = it * 256 + tid;          // 0..3071
        int row = lin >> 4, sg = lin & 15;
        *(int4*)&Qs[row][sg * 8] = *(const int4*)(q_bf + qbase + (long)row * DIM + sg * 8);
    }
    __syncthreads();

    int wv = tid >> 6, lane = tid & 63;
    int quad = lane >> 4, l15 = lane & 15;
    f32x4 acc[4][3];
    #pragma unroll
    for (int mt = 0; mt < 4; ++mt)
        #pragma unroll
        for (int nt = 0; nt < 3; ++nt) acc[mt][nt] = (f32x4){0.f, 0.f, 0.f, 0.f};

    #pragma unroll
    for (int kb = 0; kb < 4; ++kb) {
        bf16x8 afr[4], bfr[3];
        #pragma unroll
        for (int mt = 0; mt < 4; ++mt)
            afr[mt] = *(bf16x8*)&Ks[mt * 16 + l15][kb * 32 + quad * 8];
        #pragma unroll
        for (int nt = 0; nt < 3; ++nt)
            bfr[nt] = *(bf16x8*)&Qs[wv * 48 + nt * 16 + l15][kb * 32 + quad * 8];
        #pragma unroll
        for (int mt = 0; mt < 4; ++mt)
            #pragma unroll
            for (int nt = 0; nt < 3; ++nt)
                acc[mt][nt] = __builtin_amdgcn_mfma_f32_16x16x32_bf16(
                    afr[mt], bfr[nt], acc[mt][nt], 0, 0, 0);
    }
    __syncthreads();   // Ks/Qs dead; S aliases them
    #pragma unroll
    for (int mt = 0; mt < 4; ++mt)
        #pragma unroll
        for (int nt = 0; nt < 3; ++nt)
            #pragma unroll
            for (int r = 0; r < 4; ++r)
                S[mt * 16 + quad * 4 + r][wv * 48 + nt * 16 + l15] = acc[mt][nt][r];
    __syncthreads();

    if (tid < 64) {
        int w = tid;
        int cw = min(max(w, 1), WOq - 2);
        float scale = expf(tau[0]);
        float l[9];
        #pragma unroll
        for (int t = 0; t < 9; ++t) {
            int j = (t / 3) * 64 + cw - 1 + (t % 3);
            l[t] = (S[w][j] + rpb[g * 9 + t]) * scale;
        }
        float m = l[0];
        #pragma unroll
        for (int t = 1; t < 9; ++t) m = fmaxf(m, l[t]);
        float e[9], s = 0.f;
        #pragma unroll
        for (int t = 0; t < 9; ++t) { e[t] = __expf(l[t] - m); s += e[t]; }
        float inv = 1.0f / s;
        long cell = (long)(b * 4 + g) * NPOS + h * 64 + w;
        #pragma unroll
        for (int t = 0; t < 9; ++t) {
            float a = e[t] * inv + EPS_A;
            int j = (t / 3) * 64 + cw - 1 + (t % 3);
            attn_out[cell * 9 + t] = a;
            atomicAdd(&colacc[j], a);
        }
    }
    __syncthreads();
    if (tid < 192) atomicAdd(&col_sums[b * NPOS + r0 * 64 + tid], colacc[tid]);
}

// ---------------------------------------------------------------------------
// acol_upd v2: block = (b, h-row), 512 threads. V window (3 rows x 64 w)
// staged in LDS per g; each thread register-accumulates 16 (w,c) outputs.
// XCD-bijective swizzle: consecutive h on one XCD -> V-row overlap hits L2.
__global__ __launch_bounds__(512) void acol_upd_kernel(
        const float* __restrict__ attn_out,
        const float* __restrict__ col_sums,
        const unsigned short* __restrict__ v_bf,
        float* __restrict__ acol_out,
        float* __restrict__ x_out) {
    __shared__ unsigned short Vs[3 * 64 * 128];   // 49152 B
    __shared__ float sA[64][9];
    int bid = blockIdx.x;
    bid = (bid & 7) * 32 + (bid >> 3);            // bijective (256 % 8 == 0)
    int b = bid >> 6, h = bid & 63;
    int ch = min(max(h, 1), HOq - 2);
    int r0 = ch - 1;
    int tid = threadIdx.x;                        // 0..511
    int c = tid & 127, wg4 = tid >> 7;            // wave-uniform w group

    float acc[16];
    #pragma unroll
    for (int k = 0; k < 16; ++k) acc[k] = 0.f;

    for (int g = 0; g < 4; ++g) {
        __syncthreads();
        long vgbase = ((long)(b * 4 + g) * NPOS + r0 * 64) * DIM;
        // stage V rows r0..r0+2 (192 rows x 16 int4-chunks)
        #pragma unroll
        for (int it = 0; it < 6; ++it) {
            int chunk = it * 512 + tid;           // 0..3071
            int row = chunk >> 4, sg = chunk & 15;
            *(int4*)&Vs[row * 128 + sg * 8] =
                *(const int4*)(v_bf + vgbase + (long)row * DIM + sg * 8);
        }
        // A = attn / colsum for this g (576 values)
        for (int idx = tid; idx < 576; idx += 512) {
            int w = idx / 9, t = idx % 9;
            long ci = ((long)(b * 4 + g) * NPOS + h * 64 + w) * 9 + t;
            float a = attn_out[ci];
            float cs = col_sums[b * NPOS + nb_index(h, w, t)];
            float A = a / (cs + 1e-8f);
            sA[w][t] = A;
            acol_out[ci] = A;
        }
        __syncthreads();
        #pragma unroll
        for (int k = 0; k < 16; ++k) {
            int w = wg4 * 16 + k;
            int cw = min(max(w, 1), WOq - 2);
            float a0 = 0.f;
            #pragma unroll
            for (int t = 0; t < 9; ++t) {
                int lrow = (t / 3) * 64 + cw + (t % 3) - 1;
                a0 += sA[w][t] * bf2f(Vs[lrow * 128 + c]);
            }
            acc[k] += a0;
        }
    }
    long xbase = ((long)b * NPOS + h * 64) * DIM;
    #pragma unroll
    for (int k = 0; k < 16; ++k) {
        int w = wg4 * 16 + k;
        x_out[xbase + (long)w * DIM + c] += acc[k];
    }
}

// ---------------------------------------------------------------------------
// Fused MFMA MLP: h=gelu(x@w1+b1); o=h@w2+b2; x += LN(o). 64 tokens/block.
__global__ __launch_bounds__(256) void mlp_mfma_kernel(
        float* __restrict__ x_out,
        const unsigned short* __restrict__ w1t,  // [256][128]
        const unsigned short* __restrict__ w2t,  // [128][256]
        const float* __restrict__ b1, const float* __restrict__ b2,
        const float* __restrict__ ln_g, const float* __restrict__ ln_b) {
    __shared__ __align__(16) char smem[51200];
    unsigned short (*sxbf)[136] = (unsigned short(*)[136])smem;          // 17408 B
    unsigned short (*h_s)[264]  = (unsigned short(*)[264])(smem + 17408); // 33792 B
    float (*o_s)[132]           = (float(*)[132])smem;                    // aliased

    int tid = threadIdx.x;
    long base = (long)blockIdx.x * 64;
    int wv = tid >> 6, lane = tid & 63;
    int quad = lane >> 4, l15 = lane & 15;

    // stage x -> bf16
    {
        int r = tid >> 2, seg = tid & 3;
        const float* xr = x_out + (base + r) * DIM + seg * 32;
        #pragma unroll
        for (int j = 0; j < 4; ++j) {
            float4 a = *(const float4*)(xr + j * 8);
            float4 c = *(const float4*)(xr + j * 8 + 4);
            unsigned short u[8] = {f2bf(a.x), f2bf(a.y), f2bf(a.z), f2bf(a.w),
                                   f2bf(c.x), f2bf(c.y), f2bf(c.z), f2bf(c.w)};
            *(int4*)&sxbf[r][seg * 32 + j * 8] = *(int4*)u;
        }
    }
    __syncthreads();

    // GEMM1: M=64, N=256 (wave wv -> cols wv*64..+64), K=128
    f32x4 acc1[4][4];
    #pragma unroll
    for (int mt = 0; mt < 4; ++mt)
        #pragma unroll
        for (int nt = 0; nt < 4; ++nt) acc1[mt][nt] = (f32x4){0.f, 0.f, 0.f, 0.f};
    #pragma unroll
    for (int kb = 0; kb < 4; ++kb) {
        bf16x8 afr[4], bfr[4];
        #pragma unroll
        for (int mt = 0; mt < 4; ++mt)
            afr[mt] = *(bf16x8*)&sxbf[mt * 16 + l15][kb * 32 + quad * 8];
        #pragma unroll
        for (int nt = 0; nt < 4; ++nt) {
            int n = wv * 64 + nt * 16 + l15;
            bfr[nt] = *(const bf16x8*)(w1t + (long)n * DIM + kb * 32 + quad * 8);
        }
        #pragma unroll
        for (int mt = 0; mt < 4; ++mt)
            #pragma unroll
            for (int nt = 0; nt < 4; ++nt)
                acc1[mt][nt] = __builtin_amdgcn_mfma_f32_16x16x32_bf16(
                    afr[mt], bfr[nt], acc1[mt][nt], 0, 0, 0);
    }
    // bias + gelu -> h_s (bf16)
    #pragma unroll
    for (int nt = 0; nt < 4; ++nt) {
        int col = wv * 64 + nt * 16 + l15;
        float bj = b1[col];
        #pragma unroll
        for (int mt = 0; mt < 4; ++mt)
            #pragma unroll
            for (int r = 0; r < 4; ++r) {
                int row = mt * 16 + quad * 4 + r;
                float hv = acc1[mt][nt][r] + bj;
                hv = 0.5f * hv * (1.0f + erff(hv * 0.70710678118654752f));
                h_s[row][col] = f2bf(hv);
            }
    }
    __syncthreads();

    // GEMM2: M=64, N=128 (wave wv -> cols wv*32..+32), K=256
    f32x4 acc2[4][2];
    #pragma unroll
    for (int mt = 0; mt < 4; ++mt)
        #pragma unroll
        for (int nt = 0; nt < 2; ++nt) acc2[mt][nt] = (f32x4){0.f, 0.f, 0.f, 0.f};
    #pragma unroll
    for (int kb = 0; kb < 8; ++kb) {
        bf16x8 afr[4], bfr[2];
        #pragma unroll
        for (int mt = 0; mt < 4; ++mt)
            afr[mt] = *(bf16x8*)&h_s[mt * 16 + l15][kb * 32 + quad * 8];
        #pragma unroll
        for (int nt = 0; nt < 2; ++nt) {
            int n = wv * 32 + nt * 16 + l15;
            bfr[nt] = *(const bf16x8*)(w2t + (long)n * 256 + kb * 32 + quad * 8);
        }
        #pragma unroll
        for (int mt = 0; mt < 4; ++mt)
            #pragma unroll
            for (int nt = 0; nt < 2; ++nt)
                acc2[mt][nt] = __builtin_amdgcn_mfma_f32_16x16x32_bf16(
                    afr[mt], bfr[nt], acc2[mt][nt], 0, 0, 0);
    }
    __syncthreads();   // h_s dead; safe to write aliased o_s

    #pragma unroll
    for (int nt = 0; nt < 2; ++nt) {
        int col = wv * 32 + nt * 16 + l15;
        float bj = b2[col];
        #pragma unroll
        for (int mt = 0; mt < 4; ++mt)
            #pragma unroll
            for (int r = 0; r < 4; ++r)
                o_s[mt * 16 + quad * 4 + r][col] = acc2[mt][nt][r] + bj;
    }
    __syncthreads();

    // LN(o) + residual. 4 threads per row, 32 cols each.
    {
        int r = tid >> 2, qq = tid & 3;
        float s = 0.f, ss = 0.f;
        #pragma unroll
        for (int j = 0; j < 32; ++j) {
            float v = o_s[r][qq * 32 + j];
            s += v; ss += v * v;
        }
        s  += __shfl_xor(s, 1, 64);  ss += __shfl_xor(ss, 1, 64);
        s  += __shfl_xor(s, 2, 64);  ss += __shfl_xor(ss, 2, 64);
        float mu = s * (1.0f / DIM);
        float var = fmaxf(ss * (1.0f / DIM) - mu * mu, 0.0f);
        float rstd = rsqrtf(var + EPS_LN);
        float* xr = x_out + (base + r) * DIM + qq * 32;
        #pragma unroll
        for (int j = 0; j < 32; ++j) {
            int c = qq * 32 + j;
            xr[j] = xr[j] + (o_s[r][c] - mu) * rstd * ln_g[c] + ln_b[c];
        }
    }
}

// ---------------------------------------------------------------------------
extern "C" void kernel_launch(void* const* d_in, const int* in_sizes, int n_in,
                              void* d_out, int out_size, void* d_ws, size_t ws_size,
                              hipStream_t stream) {
    const float* x        = (const float*)d_in[0];
    const float* conv_w   = (const float*)d_in[1];
    const float* q_w      = (const float*)d_in[2];
    const float* k_w      = (const float*)d_in[3];
    const float* v_w      = (const float*)d_in[4];
    const float* mlp_w1   = (const float*)d_in[5];
    const float* mlp_b1   = (const float*)d_in[6];
    const float* mlp_w2   = (const float*)d_in[7];
    const float* mlp_b2   = (const float*)d_in[8];
    const float* ln_in_g  = (const float*)d_in[9];
    const float* ln_in_b  = (const float*)d_in[10];
    const float* ln_out_g = (const float*)d_in[11];
    const float* ln_out_b = (const float*)d_in[12];
    const float* tau      = (const float*)d_in[13];
    const float* rpb      = (const float*)d_in[14];

    float* out_x    = (float*)d_out;
    float* out_attn = out_x + (long)BN * NPOS * DIM;
    float* out_acol = out_attn + (long)BN * 4 * NPOS * 9;

    char* ws = (char*)d_ws;
    unsigned short* k_bf = (unsigned short*)ws; ws += (long)BN * 4 * NPOS * DIM * 4;  // slot kept f32-sized
    unsigned short* v_bf = (unsigned short*)ws; ws += (long)BN * 4 * NPOS * DIM * 4;  // slot kept f32-sized
    unsigned short* x_bf = (unsigned short*)ws;
    unsigned short* q_bf = (unsigned short*)ws;  // q aliases x_bf (setup-only)
    ws += (long)BN * NTOK * DIM * 2;
    unsigned short* xln_bf = (unsigned short*)ws; ws += (long)BN * NTOK * DIM * 2;
    unsigned short* wt_conv = (unsigned short*)ws; ws += 1152L * DIM * 2;
    unsigned short* kwt = (unsigned short*)ws;     ws += (long)DIM * DIM * 2;
    unsigned short* vwt = (unsigned short*)ws;     ws += (long)DIM * DIM * 2;
    unsigned short* qwt = (unsigned short*)ws;     ws += (long)DIM * DIM * 2;
    unsigned short* w1t = (unsigned short*)ws;     ws += 256L * DIM * 2;
    unsigned short* w2t = (unsigned short*)ws;     ws += 256L * DIM * 2;
    float* col_sums = (float*)ws;       ws += (long)BN * NPOS * 4;

    prep_ln_kernel<<<16384, 256, 0, stream>>>(x, ln_in_g, ln_in_b, x_bf, xln_bf);
    conv_wt_kernel<<<dim3(128, 9), 128, 0, stream>>>(conv_w, wt_conv);
    wt_all_kernel<<<128, 128, 0, stream>>>(k_w, v_w, q_w, mlp_w1, mlp_w2,
                                           kwt, vwt, qwt, w1t, w2t);

    kv_mfma_kernel<<<1024, 256, 0, stream>>>(x_bf, xln_bf, kwt, vwt, k_bf, v_bf);
    conv_mfma_kernel<<<256, 256, 0, stream>>>(x_bf, wt_conv, ln_out_g, ln_out_b, out_x);

    for (int it = 0; it < 3; ++it) {
        q_mfma_kernel<<<256, 256, 0, stream>>>(out_x, qwt, ln_out_g, ln_out_b, q_bf);
        zero_kernel<<<(BN * NPOS + 255) / 256, 256, 0, stream>>>(col_sums, BN * NPOS);
        attn_mfma_kernel<<<1024, 256, 0, stream>>>(k_bf, q_bf, rpb, tau, out_attn, col_sums);
        acol_upd_kernel<<<256, 512, 0, stream>>>(out_attn, col_sums, v_bf, out_acol, out_x);
        mlp_mfma_kernel<<<256, 256, 0, stream>>>(out_x, w1t, w2t, mlp_b1, mlp_b2,
                                                 ln_out_g, ln_out_b);
    }
}

// Round 9
// 320.143 us; speedup vs baseline: 1.0779x; 1.0779x over previous
//
#include <hip/hip_runtime.h>
#include <hip/hip_bf16.h>
#include <math.h>

#define BN 4
#define HIq 128
#define WIq 128
#define DIM 128
#define HOq 64
#define WOq 64
#define NPOS 4096      // HO*WO
#define NTOK 16384     // HI*WI
#define EPS_LN 1e-5f
#define EPS_A 1e-6f

typedef __attribute__((ext_vector_type(8))) short bf16x8;
typedef __attribute__((ext_vector_type(4))) float f32x4;

__device__ __forceinline__ unsigned short f2bf(float f) {
    unsigned int u = __float_as_uint(f);
    u = (u + 0x7FFFu + ((u >> 16) & 1u)) >> 16;
    return (unsigned short)u;
}

__device__ __forceinline__ float bf2f(unsigned short u) {
    return __uint_as_float((unsigned int)u << 16);
}

__device__ __forceinline__ int nb_index(int h, int w, int t) {
    int ch = min(max(h, 1), HOq - 2);
    int cw = min(max(w, 1), WOq - 2);
    int dr = t / 3 - 1, dc = t % 3 - 1;
    return (ch + dr) * WOq + (cw + dc);
}

// ---------------------------------------------------------------------------
// x -> bf16, LN(x) -> bf16. Wave wv handles row blockIdx*4+wv.
// float2 loads, packed 2xbf16 stores (proven in round 7).
__global__ void prep_ln_kernel(const float* __restrict__ x,
                               const float* __restrict__ g,
                               const float* __restrict__ bb,
                               unsigned short* __restrict__ x_bf,
                               unsigned short* __restrict__ xln_bf) {
    int tid = threadIdx.x, wv = tid >> 6, lane = tid & 63;
    long row = (long)blockIdx.x * 4 + wv;
    const float2* xr = (const float2*)(x + row * DIM);
    float2 v = xr[lane];
    float s = v.x + v.y, ss = v.x * v.x + v.y * v.y;
    #pragma unroll
    for (int off = 32; off; off >>= 1) {
        s  += __shfl_xor(s, off, 64);
        ss += __shfl_xor(ss, off, 64);
    }
    float mu = s * (1.0f / DIM);
    float var = fmaxf(ss * (1.0f / DIM) - mu * mu, 0.0f);
    float rstd = rsqrtf(var + EPS_LN);
    float2 gg = ((const float2*)g)[lane];
    float2 bv = ((const float2*)bb)[lane];
    unsigned int xo = (unsigned int)f2bf(v.x) | ((unsigned int)f2bf(v.y) << 16);
    *(unsigned int*)&x_bf[row * DIM + 2 * lane] = xo;
    unsigned int lo = (unsigned int)f2bf((v.x - mu) * rstd * gg.x + bv.x)
                    | ((unsigned int)f2bf((v.y - mu) * rstd * gg.y + bv.y) << 16);
    *(unsigned int*)&xln_bf[row * DIM + 2 * lane] = lo;
}

// ---------------------------------------------------------------------------
// conv_w [O][I][3][3] -> wt [o][tap*128+i] bf16
__global__ void conv_wt_kernel(const float* __restrict__ cw, unsigned short* __restrict__ wt) {
    int o = blockIdx.x, tap = blockIdx.y, i = threadIdx.x;
    wt[(long)o * 1152 + tap * 128 + i] = f2bf(cw[((long)o * 128 + i) * 9 + tap]);
}

// k_w/v_w/q_w [i][o] -> [o][i] bf16 ; mlp_w1 [i][j](128x256) -> [j][i] ;
// mlp_w2 [j][o](256x128) -> [o][j]
__global__ void wt_all_kernel(const float* __restrict__ kw, const float* __restrict__ vw,
                              const float* __restrict__ qw,
                              const float* __restrict__ w1, const float* __restrict__ w2,
                              unsigned short* __restrict__ kwt, unsigned short* __restrict__ vwt,
                              unsigned short* __restrict__ qwt,
                              unsigned short* __restrict__ w1t, unsigned short* __restrict__ w2t) {
    int o = blockIdx.x, i = threadIdx.x;   // 128 x 128
    kwt[o * DIM + i] = f2bf(kw[i * DIM + o]);
    vwt[o * DIM + i] = f2bf(vw[i * DIM + o]);
    qwt[o * DIM + i] = f2bf(qw[i * DIM + o]);
    // w1: [i=128][j=256] -> w1t[j=256][i=128]
    w1t[(2 * o) * DIM + i]     = f2bf(w1[i * 256 + 2 * o]);
    w1t[(2 * o + 1) * DIM + i] = f2bf(w1[i * 256 + 2 * o + 1]);
    // w2: [j=256][o=128] -> w2t[o=128][j=256]
    w2t[o * 256 + i]       = f2bf(w2[i * DIM + o]);
    w2t[o * 256 + 128 + i] = f2bf(w2[(128 + i) * DIM + o]);
}

// ---------------------------------------------------------------------------
// Conv as implicit-im2col MFMA GEMM with fused LN epilogue (round-6 proven).
// Full-row LDS staging per tap -> 18 barriers/block; inner loop pure LDS+MFMA.
__global__ __launch_bounds__(256) void conv_mfma_kernel(
        const unsigned short* __restrict__ x_bf,
        const unsigned short* __restrict__ wt,
        const float* __restrict__ ln_g, const float* __restrict__ ln_b,
        float* __restrict__ out_x) {
    __shared__ __align__(16) char smem[52224];
    unsigned short (*As)[136] = (unsigned short(*)[136])smem;            // 17408 B
    unsigned short (*Bs)[136] = (unsigned short(*)[136])(smem + 17408);  // 34816 B
    float (*o_s)[132]         = (float(*)[132])smem;                     // aliased, 33792 B

    int tid = threadIdx.x;
    int wv = tid >> 6, lane = tid & 63;
    int quad = lane >> 4, l15 = lane & 15;
    int wr = wv >> 1, wc = wv & 1;
    int b = blockIdx.x >> 6, ho = blockIdx.x & 63;

    f32x4 acc[2][4];
    #pragma unroll
    for (int mt = 0; mt < 2; ++mt)
        #pragma unroll
        for (int nt = 0; nt < 4; ++nt) acc[mt][nt] = (f32x4){0.f, 0.f, 0.f, 0.f};

    for (int tap = 0; tap < 9; ++tap) {
        int kh = tap / 3, kw = tap % 3;
        int hi = 2 * ho - 1 + kh;
        bool hok = (hi >= 0) && (hi < HIq);
        __syncthreads();
        // stage A: 64 rows x 16 int4-chunks (full 128 channels)
        #pragma unroll
        for (int it = 0; it < 4; ++it) {
            int c = it * 256 + tid;
            int row = c >> 4, sg = c & 15;
            int wi = 2 * row - 1 + kw;
            int4 av = {0, 0, 0, 0};
            if (hok && wi >= 0 && wi < WIq)
                av = *(const int4*)(x_bf + (((long)b * HIq + hi) * WIq + wi) * DIM + sg * 8);
            *(int4*)&As[row][sg * 8] = av;
        }
        // stage B: 128 rows x 16 chunks
        #pragma unroll
        for (int it = 0; it < 8; ++it) {
            int c = it * 256 + tid;
            int row = c >> 4, sg = c & 15;
            *(int4*)&Bs[row][sg * 8] =
                *(const int4*)(wt + (long)row * 1152 + tap * 128 + sg * 8);
        }
        __syncthreads();
        #pragma unroll
        for (int ib = 0; ib < 4; ++ib) {
            bf16x8 afr[2], bfr[4];
            #pragma unroll
            for (int mt = 0; mt < 2; ++mt)
                afr[mt] = *(bf16x8*)&As[wr * 32 + mt * 16 + l15][ib * 32 + quad * 8];
            #pragma unroll
            for (int nt = 0; nt < 4; ++nt)
                bfr[nt] = *(bf16x8*)&Bs[wc * 64 + nt * 16 + l15][ib * 32 + quad * 8];
            #pragma unroll
            for (int mt = 0; mt < 2; ++mt)
                #pragma unroll
                for (int nt = 0; nt < 4; ++nt)
                    acc[mt][nt] = __builtin_amdgcn_mfma_f32_16x16x32_bf16(
                        afr[mt], bfr[nt], acc[mt][nt], 0, 0, 0);
        }
    }
    __syncthreads();   // As/Bs dead; o_s aliases them
    #pragma unroll
    for (int mt = 0; mt < 2; ++mt)
        #pragma unroll
        for (int r = 0; r < 4; ++r) {
            int wo = wr * 32 + mt * 16 + quad * 4 + r;
            #pragma unroll
            for (int nt = 0; nt < 4; ++nt) {
                int col = wc * 64 + nt * 16 + l15;
                o_s[wo][col] = acc[mt][nt][r];
            }
        }
    __syncthreads();

    // LN over channels per position; 4 threads per row, 32 cols each.
    {
        int r = tid >> 2, qq = tid & 3;
        float s = 0.f, ss = 0.f;
        #pragma unroll
        for (int j = 0; j < 32; ++j) {
            float v = o_s[r][qq * 32 + j];
            s += v; ss += v * v;
        }
        s  += __shfl_xor(s, 1, 64);  ss += __shfl_xor(ss, 1, 64);
        s  += __shfl_xor(s, 2, 64);  ss += __shfl_xor(ss, 2, 64);
        float mu = s * (1.0f / DIM);
        float var = fmaxf(ss * (1.0f / DIM) - mu * mu, 0.0f);
        float rstd = rsqrtf(var + EPS_LN);
        long outb = ((long)b * NPOS + ho * WOq) * DIM;
        float* xr = out_x + outb + (long)r * DIM + qq * 32;
        #pragma unroll
        for (int j = 0; j < 32; ++j) {
            int c = qq * 32 + j;
            xr[j] = (o_s[r][c] - mu) * rstd * ln_g[c] + ln_b[c];
        }
    }
}

// ---------------------------------------------------------------------------
// kv dual MFMA GEMM. K and V both written as bf16.
__global__ __launch_bounds__(256) void kv_mfma_kernel(
        const unsigned short* __restrict__ x_bf,
        const unsigned short* __restrict__ xln_bf,
        const unsigned short* __restrict__ kwt,
        const unsigned short* __restrict__ vwt,
        unsigned short* __restrict__ k_bf, unsigned short* __restrict__ v_bf) {
    __shared__ unsigned short Ak[64][40], Av[64][40];
    __shared__ unsigned short Bk[128][40], Bv[128][40];
    int tid = threadIdx.x;
    int wv = tid >> 6, lane = tid & 63;
    int quad = lane >> 4, l15 = lane & 15;
    int wr = wv >> 1, wc = wv & 1;
    long tokBase = (long)blockIdx.x * 64;

    f32x4 acck[2][4], accv[2][4];
    #pragma unroll
    for (int mt = 0; mt < 2; ++mt)
        #pragma unroll
        for (int nt = 0; nt < 4; ++nt) {
            acck[mt][nt] = (f32x4){0.f, 0.f, 0.f, 0.f};
            accv[mt][nt] = (f32x4){0.f, 0.f, 0.f, 0.f};
        }

    int m = tid >> 2, seg = tid & 3;
    #pragma unroll
    for (int ib = 0; ib < 4; ++ib) {
        __syncthreads();
        *(int4*)&Ak[m][seg * 8] = *(const int4*)(xln_bf + (tokBase + m) * DIM + ib * 32 + seg * 8);
        *(int4*)&Av[m][seg * 8] = *(const int4*)(x_bf   + (tokBase + m) * DIM + ib * 32 + seg * 8);
        #pragma unroll
        for (int r2 = 0; r2 < 2; ++r2) {
            int lin = r2 * 256 + tid;
            int n = lin >> 2, sg = lin & 3;
            *(int4*)&Bk[n][sg * 8] = *(const int4*)(kwt + (long)n * DIM + ib * 32 + sg * 8);
            *(int4*)&Bv[n][sg * 8] = *(const int4*)(vwt + (long)n * DIM + ib * 32 + sg * 8);
        }
        __syncthreads();
        bf16x8 ak[2], av2[2], bk[4], bv[4];
        #pragma unroll
        for (int mt = 0; mt < 2; ++mt) {
            ak[mt]  = *(bf16x8*)&Ak[wr * 32 + mt * 16 + l15][quad * 8];
            av2[mt] = *(bf16x8*)&Av[wr * 32 + mt * 16 + l15][quad * 8];
        }
        #pragma unroll
        for (int nt = 0; nt < 4; ++nt) {
            bk[nt] = *(bf16x8*)&Bk[wc * 64 + nt * 16 + l15][quad * 8];
            bv[nt] = *(bf16x8*)&Bv[wc * 64 + nt * 16 + l15][quad * 8];
        }
        #pragma unroll
        for (int mt = 0; mt < 2; ++mt)
            #pragma unroll
            for (int nt = 0; nt < 4; ++nt) {
                acck[mt][nt] = __builtin_amdgcn_mfma_f32_16x16x32_bf16(ak[mt],  bk[nt], acck[mt][nt], 0, 0, 0);
                accv[mt][nt] = __builtin_amdgcn_mfma_f32_16x16x32_bf16(av2[mt], bv[nt], accv[mt][nt], 0, 0, 0);
            }
    }
    #pragma unroll
    for (int mt = 0; mt < 2; ++mt)
        #pragma unroll
        for (int r = 0; r < 4; ++r) {
            long tok = tokBase + wr * 32 + mt * 16 + quad * 4 + r;
            int b = (int)(tok >> 14);
            int pix = (int)(tok & 16383);
            int ih = pix >> 7, iw = pix & 127;
            int g = (ih & 1) * 2 + (iw & 1);
            int pos = (ih >> 1) * WOq + (iw >> 1);
            long base = ((long)(b * 4 + g) * NPOS + pos) * DIM;
            #pragma unroll
            for (int nt = 0; nt < 4; ++nt) {
                int col = wc * 64 + nt * 16 + l15;
                k_bf[base + col] = f2bf(acck[mt][nt][r]);
                v_bf[base + col] = f2bf(accv[mt][nt][r]);
            }
        }
}

// ---------------------------------------------------------------------------
// q = LN(x_out)@q_w via MFMA, output bf16. Also zeroes col_sums (fused
// zero_kernel: first 16384 threads of the grid; same-stream ordering makes
// it visible to the subsequent attn launch).
__global__ __launch_bounds__(256) void q_mfma_kernel(
        const float* __restrict__ x_out,
        const unsigned short* __restrict__ qwt,
        const float* __restrict__ ln_g, const float* __restrict__ ln_b,
        unsigned short* __restrict__ q,
        float* __restrict__ col_sums) {
    __shared__ unsigned short sxbf[64][136];
    int tid = threadIdx.x;
    long base = (long)blockIdx.x * 64;

    int zi = blockIdx.x * 256 + tid;
    if (zi < BN * NPOS) col_sums[zi] = 0.0f;

    // stage: LN(x_out) -> bf16. 4 threads per row; thread covers 32 cols.
    {
        int r = tid >> 2, qq = tid & 3;
        const float* xr = x_out + (base + r) * DIM + qq * 32;
        float vv[32];
        float s = 0.f, ss = 0.f;
        #pragma unroll
        for (int j = 0; j < 8; ++j) {
            float4 v4 = *(const float4*)(xr + j * 4);
            vv[j * 4 + 0] = v4.x; vv[j * 4 + 1] = v4.y;
            vv[j * 4 + 2] = v4.z; vv[j * 4 + 3] = v4.w;
            s += v4.x + v4.y + v4.z + v4.w;
            ss += v4.x * v4.x + v4.y * v4.y + v4.z * v4.z + v4.w * v4.w;
        }
        s  += __shfl_xor(s, 1, 64);  ss += __shfl_xor(ss, 1, 64);
        s  += __shfl_xor(s, 2, 64);  ss += __shfl_xor(ss, 2, 64);
        float mu = s * (1.0f / DIM);
        float var = fmaxf(ss * (1.0f / DIM) - mu * mu, 0.0f);
        float rstd = rsqrtf(var + EPS_LN);
        #pragma unroll
        for (int j = 0; j < 32; ++j) {
            int c = qq * 32 + j;
            sxbf[r][c] = f2bf((vv[j] - mu) * rstd * ln_g[c] + ln_b[c]);
        }
    }
    __syncthreads();

    int wv = tid >> 6, lane = tid & 63;
    int quad = lane >> 4, l15 = lane & 15;
    f32x4 acc[4][2];
    #pragma unroll
    for (int mt = 0; mt < 4; ++mt)
        #pragma unroll
        for (int nt = 0; nt < 2; ++nt) acc[mt][nt] = (f32x4){0.f, 0.f, 0.f, 0.f};

    #pragma unroll
    for (int kb = 0; kb < 4; ++kb) {
        bf16x8 afr[4], bfr[2];
        #pragma unroll
        for (int mt = 0; mt < 4; ++mt)
            afr[mt] = *(bf16x8*)&sxbf[mt * 16 + l15][kb * 32 + quad * 8];
        #pragma unroll
        for (int nt = 0; nt < 2; ++nt) {
            int n = wv * 32 + nt * 16 + l15;
            bfr[nt] = *(const bf16x8*)(qwt + (long)n * DIM + kb * 32 + quad * 8);
        }
        #pragma unroll
        for (int mt = 0; mt < 4; ++mt)
            #pragma unroll
            for (int nt = 0; nt < 2; ++nt)
                acc[mt][nt] = __builtin_amdgcn_mfma_f32_16x16x32_bf16(
                    afr[mt], bfr[nt], acc[mt][nt], 0, 0, 0);
    }
    #pragma unroll
    for (int mt = 0; mt < 4; ++mt)
        #pragma unroll
        for (int r = 0; r < 4; ++r) {
            long tok = base + mt * 16 + quad * 4 + r;
            #pragma unroll
            for (int nt = 0; nt < 2; ++nt) {
                int col = wv * 32 + nt * 16 + l15;
                q[tok * DIM + col] = f2bf(acc[mt][nt][r]);
            }
        }
}

// ---------------------------------------------------------------------------
// attn (MFMA): block = (b, g, h-row). S = K_strip(64x128) @ Q_strip(192x128)^T
// via 192 MFMAs; softmax by 64 threads from LDS; per-block LDS col-sum
// accumulation (192 global atomics/block). Round-6 proven.
__global__ __launch_bounds__(256) void attn_mfma_kernel(
        const unsigned short* __restrict__ k_bf,
        const unsigned short* __restrict__ q_bf,
        const float* __restrict__ rpb,
        const float* __restrict__ tau,
        float* __restrict__ attn_out,
        float* __restrict__ col_sums) {
    __shared__ __align__(16) char smem[69632];
    __shared__ float colacc[192];
    unsigned short (*Ks)[136] = (unsigned short(*)[136])smem;            // 17408 B
    unsigned short (*Qs)[136] = (unsigned short(*)[136])(smem + 17408);  // 52224 B
    float (*S)[193]           = (float(*)[193])smem;                     // 49408 B aliased

    int tid = threadIdx.x;
    int bid = blockIdx.x;
    int h = bid & 63, g = (bid >> 6) & 3, b = bid >> 8;
    int r0 = min(max(h, 1), HOq - 2) - 1;   // first Q strip row

    long kbase = ((long)(b * 4 + g) * NPOS + h * 64) * DIM;
    long qbase = ((long)b * NPOS + r0 * 64) * DIM;

    if (tid < 192) colacc[tid] = 0.f;

    // stage K (64 rows x 16 chunks) + Q (192 rows x 16 chunks), int4-vectorized
    #pragma unroll
    for (int it = 0; it < 4; ++it) {
        int lin = it * 256 + tid;          // 0..1023
        int row = lin >> 4, sg = lin & 15;
        *(int4*)&Ks[row][sg * 8] = *(const int4*)(k_bf + kbase + (long)row * DIM + sg * 8);
    }
    #pragma unroll
    for (int it = 0; it < 12; ++it) {
        int lin = it * 256 + tid;          // 0..3071
        int row = lin >> 4, sg = lin & 15;
        *(int4*)&Qs[row][sg * 8] = *(const int4*)(q_bf + qbase + (long)row * DIM + sg * 8);
    }
    __syncthreads();

    int wv = tid >> 6, lane = tid & 63;
    int quad = lane >> 4, l15 = lane & 15;
    f32x4 acc[4][3];
    #pragma unroll
    for (int mt = 0; mt < 4; ++mt)
        #pragma unroll
        for (int nt = 0; nt < 3; ++nt) acc[mt][nt] = (f32x4){0.f, 0.f, 0.f, 0.f};

    #pragma unroll
    for (int kb = 0; kb < 4; ++kb) {
        bf16x8 afr[4], bfr[3];
        #pragma unroll
        for (int mt = 0; mt < 4; ++mt)
            afr[mt] = *(bf16x8*)&Ks[mt * 16 + l15][kb * 32 + quad * 8];
        #pragma unroll
        for (int nt = 0; nt < 3; ++nt)
            bfr[nt] = *(bf16x8*)&Qs[wv * 48 + nt * 16 + l15][kb * 32 + quad * 8];
        #pragma unroll
        for (int mt = 0; mt < 4; ++mt)
            #pragma unroll
            for (int nt = 0; nt < 3; ++nt)
                acc[mt][nt] = __builtin_amdgcn_mfma_f32_16x16x32_bf16(
                    afr[mt], bfr[nt], acc[mt][nt], 0, 0, 0);
    }
    __syncthreads();   // Ks/Qs dead; S aliases them
    #pragma unroll
    for (int mt = 0; mt < 4; ++mt)
        #pragma unroll
        for (int nt = 0; nt < 3; ++nt)
            #pragma unroll
            for (int r = 0; r < 4; ++r)
                S[mt * 16 + quad * 4 + r][wv * 48 + nt * 16 + l15] = acc[mt][nt][r];
    __syncthreads();

    if (tid < 64) {
        int w = tid;
        int cw = min(max(w, 1), WOq - 2);
        float scale = expf(tau[0]);
        float l[9];
        #pragma unroll
        for (int t = 0; t < 9; ++t) {
            int j = (t / 3) * 64 + cw - 1 + (t % 3);
            l[t] = (S[w][j] + rpb[g * 9 + t]) * scale;
        }
        float m = l[0];
        #pragma unroll
        for (int t = 1; t < 9; ++t) m = fmaxf(m, l[t]);
        float e[9], s = 0.f;
        #pragma unroll
        for (int t = 0; t < 9; ++t) { e[t] = __expf(l[t] - m); s += e[t]; }
        float inv = 1.0f / s;
        long cell = (long)(b * 4 + g) * NPOS + h * 64 + w;
        #pragma unroll
        for (int t = 0; t < 9; ++t) {
            float a = e[t] * inv + EPS_A;
            int j = (t / 3) * 64 + cw - 1 + (t % 3);
            attn_out[cell * 9 + t] = a;
            atomicAdd(&colacc[j], a);
        }
    }
    __syncthreads();
    if (tid < 192) atomicAdd(&col_sums[b * NPOS + r0 * 64 + tid], colacc[tid]);
}

// ---------------------------------------------------------------------------
// acol_upd (round-6 proven structure): 16384 blocks x 128 threads, bf16 V.
__global__ void acol_upd_kernel(const float* __restrict__ attn_out,
                                const float* __restrict__ col_sums,
                                const unsigned short* __restrict__ v_bf,
                                float* __restrict__ acol_out,
                                float* __restrict__ x_out) {
    __shared__ float sA[36];
    int tid = threadIdx.x;
    int row = blockIdx.x;
    int b = row >> 12, pos = row & 4095;
    int h = pos >> 6, w = pos & 63;

    if (tid < 36) {
        int g = tid / 9, t = tid % 9;
        long ci = ((long)(b * 4 + g) * NPOS + pos) * 9 + t;
        float a = attn_out[ci];
        float cs = col_sums[b * NPOS + nb_index(h, w, t)];
        float A = a / (cs + 1e-8f);
        sA[tid] = A;
        acol_out[ci] = A;
    }
    __syncthreads();

    int nn[9];
    #pragma unroll
    for (int t = 0; t < 9; ++t) nn[t] = nb_index(h, w, t);

    float acc = 0.f;
    #pragma unroll
    for (int g = 0; g < 4; ++g) {
        const unsigned short* vb = v_bf + (long)(b * 4 + g) * NPOS * DIM;
        #pragma unroll
        for (int t = 0; t < 9; ++t) {
            acc += sA[g * 9 + t] * bf2f(vb[(long)nn[t] * DIM + tid]);
        }
    }
    x_out[(long)row * DIM + tid] += acc;
}

// ---------------------------------------------------------------------------
// Fused MFMA MLP: h=gelu(x@w1+b1); o=h@w2+b2; x += LN(o). 64 tokens/block.
__global__ __launch_bounds__(256) void mlp_mfma_kernel(
        float* __restrict__ x_out,
        const unsigned short* __restrict__ w1t,  // [256][128]
        const unsigned short* __restrict__ w2t,  // [128][256]
        const float* __restrict__ b1, const float* __restrict__ b2,
        const float* __restrict__ ln_g, const float* __restrict__ ln_b) {
    __shared__ __align__(16) char smem[51200];
    unsigned short (*sxbf)[136] = (unsigned short(*)[136])smem;          // 17408 B
    unsigned short (*h_s)[264]  = (unsigned short(*)[264])(smem + 17408); // 33792 B
    float (*o_s)[132]           = (float(*)[132])smem;                    // aliased

    int tid = threadIdx.x;
    long base = (long)blockIdx.x * 64;
    int wv = tid >> 6, lane = tid & 63;
    int quad = lane >> 4, l15 = lane & 15;

    // stage x -> bf16
    {
        int r = tid >> 2, seg = tid & 3;
        const float* xr = x_out + (base + r) * DIM + seg * 32;
        #pragma unroll
        for (int j = 0; j < 4; ++j) {
            float4 a = *(const float4*)(xr + j * 8);
            float4 c = *(const float4*)(xr + j * 8 + 4);
            unsigned short u[8] = {f2bf(a.x), f2bf(a.y), f2bf(a.z), f2bf(a.w),
                                   f2bf(c.x), f2bf(c.y), f2bf(c.z), f2bf(c.w)};
            *(int4*)&sxbf[r][seg * 32 + j * 8] = *(int4*)u;
        }
    }
    __syncthreads();

    // GEMM1: M=64, N=256 (wave wv -> cols wv*64..+64), K=128
    f32x4 acc1[4][4];
    #pragma unroll
    for (int mt = 0; mt < 4; ++mt)
        #pragma unroll
        for (int nt = 0; nt < 4; ++nt) acc1[mt][nt] = (f32x4){0.f, 0.f, 0.f, 0.f};
    #pragma unroll
    for (int kb = 0; kb < 4; ++kb) {
        bf16x8 afr[4], bfr[4];
        #pragma unroll
        for (int mt = 0; mt < 4; ++mt)
            afr[mt] = *(bf16x8*)&sxbf[mt * 16 + l15][kb * 32 + quad * 8];
        #pragma unroll
        for (int nt = 0; nt < 4; ++nt) {
            int n = wv * 64 + nt * 16 + l15;
            bfr[nt] = *(const bf16x8*)(w1t + (long)n * DIM + kb * 32 + quad * 8);
        }
        #pragma unroll
        for (int mt = 0; mt < 4; ++mt)
            #pragma unroll
            for (int nt = 0; nt < 4; ++nt)
                acc1[mt][nt] = __builtin_amdgcn_mfma_f32_16x16x32_bf16(
                    afr[mt], bfr[nt], acc1[mt][nt], 0, 0, 0);
    }
    // bias + gelu -> h_s (bf16)
    #pragma unroll
    for (int nt = 0; nt < 4; ++nt) {
        int col = wv * 64 + nt * 16 + l15;
        float bj = b1[col];
        #pragma unroll
        for (int mt = 0; mt < 4; ++mt)
            #pragma unroll
            for (int r = 0; r < 4; ++r) {
                int row = mt * 16 + quad * 4 + r;
                float hv = acc1[mt][nt][r] + bj;
                hv = 0.5f * hv * (1.0f + erff(hv * 0.70710678118654752f));
                h_s[row][col] = f2bf(hv);
            }
    }
    __syncthreads();

    // GEMM2: M=64, N=128 (wave wv -> cols wv*32..+32), K=256
    f32x4 acc2[4][2];
    #pragma unroll
    for (int mt = 0; mt < 4; ++mt)
        #pragma unroll
        for (int nt = 0; nt < 2; ++nt) acc2[mt][nt] = (f32x4){0.f, 0.f, 0.f, 0.f};
    #pragma unroll
    for (int kb = 0; kb < 8; ++kb) {
        bf16x8 afr[4], bfr[2];
        #pragma unroll
        for (int mt = 0; mt < 4; ++mt)
            afr[mt] = *(bf16x8*)&h_s[mt * 16 + l15][kb * 32 + quad * 8];
        #pragma unroll
        for (int nt = 0; nt < 2; ++nt) {
            int n = wv * 32 + nt * 16 + l15;
            bfr[nt] = *(const bf16x8*)(w2t + (long)n * 256 + kb * 32 + quad * 8);
        }
        #pragma unroll
        for (int mt = 0; mt < 4; ++mt)
            #pragma unroll
            for (int nt = 0; nt < 2; ++nt)
                acc2[mt][nt] = __builtin_amdgcn_mfma_f32_16x16x32_bf16(
                    afr[mt], bfr[nt], acc2[mt][nt], 0, 0, 0);
    }
    __syncthreads();   // h_s dead; safe to write aliased o_s

    #pragma unroll
    for (int nt = 0; nt < 2; ++nt) {
        int col = wv * 32 + nt * 16 + l15;
        float bj = b2[col];
        #pragma unroll
        for (int mt = 0; mt < 4; ++mt)
            #pragma unroll
            for (int r = 0; r < 4; ++r)
                o_s[mt * 16 + quad * 4 + r][col] = acc2[mt][nt][r] + bj;
    }
    __syncthreads();

    // LN(o) + residual. 4 threads per row, 32 cols each.
    {
        int r = tid >> 2, qq = tid & 3;
        float s = 0.f, ss = 0.f;
        #pragma unroll
        for (int j = 0; j < 32; ++j) {
            float v = o_s[r][qq * 32 + j];
            s += v; ss += v * v;
        }
        s  += __shfl_xor(s, 1, 64);  ss += __shfl_xor(ss, 1, 64);
        s  += __shfl_xor(s, 2, 64);  ss += __shfl_xor(ss, 2, 64);
        float mu = s * (1.0f / DIM);
        float var = fmaxf(ss * (1.0f / DIM) - mu * mu, 0.0f);
        float rstd = rsqrtf(var + EPS_LN);
        float* xr = x_out + (base + r) * DIM + qq * 32;
        #pragma unroll
        for (int j = 0; j < 32; ++j) {
            int c = qq * 32 + j;
            xr[j] = xr[j] + (o_s[r][c] - mu) * rstd * ln_g[c] + ln_b[c];
        }
    }
}

// ---------------------------------------------------------------------------
extern "C" void kernel_launch(void* const* d_in, const int* in_sizes, int n_in,
                              void* d_out, int out_size, void* d_ws, size_t ws_size,
                              hipStream_t stream) {
    const float* x        = (const float*)d_in[0];
    const float* conv_w   = (const float*)d_in[1];
    const float* q_w      = (const float*)d_in[2];
    const float* k_w      = (const float*)d_in[3];
    const float* v_w      = (const float*)d_in[4];
    const float* mlp_w1   = (const float*)d_in[5];
    const float* mlp_b1   = (const float*)d_in[6];
    const float* mlp_w2   = (const float*)d_in[7];
    const float* mlp_b2   = (const float*)d_in[8];
    const float* ln_in_g  = (const float*)d_in[9];
    const float* ln_in_b  = (const float*)d_in[10];
    const float* ln_out_g = (const float*)d_in[11];
    const float* ln_out_b = (const float*)d_in[12];
    const float* tau      = (const float*)d_in[13];
    const float* rpb      = (const float*)d_in[14];

    float* out_x    = (float*)d_out;
    float* out_attn = out_x + (long)BN * NPOS * DIM;
    float* out_acol = out_attn + (long)BN * 4 * NPOS * 9;

    char* ws = (char*)d_ws;
    unsigned short* k_bf = (unsigned short*)ws; ws += (long)BN * 4 * NPOS * DIM * 4;  // slot kept f32-sized
    unsigned short* v_bf = (unsigned short*)ws; ws += (long)BN * 4 * NPOS * DIM * 4;  // slot kept f32-sized
    unsigned short* x_bf = (unsigned short*)ws;
    unsigned short* q_bf = (unsigned short*)ws;  // q aliases x_bf (setup-only)
    ws += (long)BN * NTOK * DIM * 2;
    unsigned short* xln_bf = (unsigned short*)ws; ws += (long)BN * NTOK * DIM * 2;
    unsigned short* wt_conv = (unsigned short*)ws; ws += 1152L * DIM * 2;
    unsigned short* kwt = (unsigned short*)ws;     ws += (long)DIM * DIM * 2;
    unsigned short* vwt = (unsigned short*)ws;     ws += (long)DIM * DIM * 2;
    unsigned short* qwt = (unsigned short*)ws;     ws += (long)DIM * DIM * 2;
    unsigned short* w1t = (unsigned short*)ws;     ws += 256L * DIM * 2;
    unsigned short* w2t = (unsigned short*)ws;     ws += 256L * DIM * 2;
    float* col_sums = (float*)ws;       ws += (long)BN * NPOS * 4;

    prep_ln_kernel<<<16384, 256, 0, stream>>>(x, ln_in_g, ln_in_b, x_bf, xln_bf);
    conv_wt_kernel<<<dim3(128, 9), 128, 0, stream>>>(conv_w, wt_conv);
    wt_all_kernel<<<128, 128, 0, stream>>>(k_w, v_w, q_w, mlp_w1, mlp_w2,
                                           kwt, vwt, qwt, w1t, w2t);

    kv_mfma_kernel<<<1024, 256, 0, stream>>>(x_bf, xln_bf, kwt, vwt, k_bf, v_bf);
    conv_mfma_kernel<<<256, 256, 0, stream>>>(x_bf, wt_conv, ln_out_g, ln_out_b, out_x);

    for (int it = 0; it < 3; ++it) {
        q_mfma_kernel<<<256, 256, 0, stream>>>(out_x, qwt, ln_out_g, ln_out_b, q_bf, col_sums);
        attn_mfma_kernel<<<1024, 256, 0, stream>>>(k_bf, q_bf, rpb, tau, out_attn, col_sums);
        acol_upd_kernel<<<16384, 128, 0, stream>>>(out_attn, col_sums, v_bf, out_acol, out_x);
        mlp_mfma_kernel<<<256, 256, 0, stream>>>(out_x, w1t, w2t, mlp_b1, mlp_b2,
                                                 ln_out_g, ln_out_b);
    }
}

// Round 10
// 307.089 us; speedup vs baseline: 1.1238x; 1.0425x over previous
//
#include <hip/hip_runtime.h>
#include <hip/hip_bf16.h>
#include <math.h>

#define BN 4
#define HIq 128
#define WIq 128
#define DIM 128
#define HOq 64
#define WOq 64
#define NPOS 4096      // HO*WO
#define NTOK 16384     // HI*WI
#define EPS_LN 1e-5f
#define EPS_A 1e-6f

typedef __attribute__((ext_vector_type(8))) short bf16x8;
typedef __attribute__((ext_vector_type(4))) float f32x4;

__device__ __forceinline__ unsigned short f2bf(float f) {
    unsigned int u = __float_as_uint(f);
    u = (u + 0x7FFFu + ((u >> 16) & 1u)) >> 16;
    return (unsigned short)u;
}

__device__ __forceinline__ float bf2f(unsigned short u) {
    return __uint_as_float((unsigned int)u << 16);
}

__device__ __forceinline__ int nb_index(int h, int w, int t) {
    int ch = min(max(h, 1), HOq - 2);
    int cw = min(max(w, 1), WOq - 2);
    int dr = t / 3 - 1, dc = t % 3 - 1;
    return (ch + dr) * WOq + (cw + dc);
}

// ---------------------------------------------------------------------------
// x -> bf16, LN(x) -> bf16. Wave wv handles row blockIdx*4+wv.
// float2 loads, packed 2xbf16 stores (proven).
__global__ void prep_ln_kernel(const float* __restrict__ x,
                               const float* __restrict__ g,
                               const float* __restrict__ bb,
                               unsigned short* __restrict__ x_bf,
                               unsigned short* __restrict__ xln_bf) {
    int tid = threadIdx.x, wv = tid >> 6, lane = tid & 63;
    long row = (long)blockIdx.x * 4 + wv;
    const float2* xr = (const float2*)(x + row * DIM);
    float2 v = xr[lane];
    float s = v.x + v.y, ss = v.x * v.x + v.y * v.y;
    #pragma unroll
    for (int off = 32; off; off >>= 1) {
        s  += __shfl_xor(s, off, 64);
        ss += __shfl_xor(ss, off, 64);
    }
    float mu = s * (1.0f / DIM);
    float var = fmaxf(ss * (1.0f / DIM) - mu * mu, 0.0f);
    float rstd = rsqrtf(var + EPS_LN);
    float2 gg = ((const float2*)g)[lane];
    float2 bv = ((const float2*)bb)[lane];
    unsigned int xo = (unsigned int)f2bf(v.x) | ((unsigned int)f2bf(v.y) << 16);
    *(unsigned int*)&x_bf[row * DIM + 2 * lane] = xo;
    unsigned int lo = (unsigned int)f2bf((v.x - mu) * rstd * gg.x + bv.x)
                    | ((unsigned int)f2bf((v.y - mu) * rstd * gg.y + bv.y) << 16);
    *(unsigned int*)&xln_bf[row * DIM + 2 * lane] = lo;
}

// ---------------------------------------------------------------------------
// Fused weight prep: conv_w -> wt ; k/v/q transpose ; w1/w2 transpose.
__global__ void wt_prep_kernel(const float* __restrict__ cw,
                               const float* __restrict__ kw, const float* __restrict__ vw,
                               const float* __restrict__ qw,
                               const float* __restrict__ w1, const float* __restrict__ w2,
                               unsigned short* __restrict__ wt,
                               unsigned short* __restrict__ kwt, unsigned short* __restrict__ vwt,
                               unsigned short* __restrict__ qwt,
                               unsigned short* __restrict__ w1t, unsigned short* __restrict__ w2t) {
    int o = blockIdx.x, i = threadIdx.x;   // 128 x 128
    #pragma unroll
    for (int tap = 0; tap < 9; ++tap)
        wt[(long)o * 1152 + tap * 128 + i] = f2bf(cw[((long)o * 128 + i) * 9 + tap]);
    kwt[o * DIM + i] = f2bf(kw[i * DIM + o]);
    vwt[o * DIM + i] = f2bf(vw[i * DIM + o]);
    qwt[o * DIM + i] = f2bf(qw[i * DIM + o]);
    w1t[(2 * o) * DIM + i]     = f2bf(w1[i * 256 + 2 * o]);
    w1t[(2 * o + 1) * DIM + i] = f2bf(w1[i * 256 + 2 * o + 1]);
    w2t[o * 256 + i]       = f2bf(w2[i * DIM + o]);
    w2t[o * 256 + 128 + i] = f2bf(w2[(128 + i) * DIM + o]);
}

// ---------------------------------------------------------------------------
// Conv as implicit-im2col MFMA GEMM with fused LN epilogue (round-6 proven).
__global__ __launch_bounds__(256) void conv_mfma_kernel(
        const unsigned short* __restrict__ x_bf,
        const unsigned short* __restrict__ wt,
        const float* __restrict__ ln_g, const float* __restrict__ ln_b,
        float* __restrict__ out_x) {
    __shared__ __align__(16) char smem[52224];
    unsigned short (*As)[136] = (unsigned short(*)[136])smem;            // 17408 B
    unsigned short (*Bs)[136] = (unsigned short(*)[136])(smem + 17408);  // 34816 B
    float (*o_s)[132]         = (float(*)[132])smem;                     // aliased, 33792 B

    int tid = threadIdx.x;
    int wv = tid >> 6, lane = tid & 63;
    int quad = lane >> 4, l15 = lane & 15;
    int wr = wv >> 1, wc = wv & 1;
    int b = blockIdx.x >> 6, ho = blockIdx.x & 63;

    f32x4 acc[2][4];
    #pragma unroll
    for (int mt = 0; mt < 2; ++mt)
        #pragma unroll
        for (int nt = 0; nt < 4; ++nt) acc[mt][nt] = (f32x4){0.f, 0.f, 0.f, 0.f};

    for (int tap = 0; tap < 9; ++tap) {
        int kh = tap / 3, kw = tap % 3;
        int hi = 2 * ho - 1 + kh;
        bool hok = (hi >= 0) && (hi < HIq);
        __syncthreads();
        #pragma unroll
        for (int it = 0; it < 4; ++it) {
            int c = it * 256 + tid;
            int row = c >> 4, sg = c & 15;
            int wi = 2 * row - 1 + kw;
            int4 av = {0, 0, 0, 0};
            if (hok && wi >= 0 && wi < WIq)
                av = *(const int4*)(x_bf + (((long)b * HIq + hi) * WIq + wi) * DIM + sg * 8);
            *(int4*)&As[row][sg * 8] = av;
        }
        #pragma unroll
        for (int it = 0; it < 8; ++it) {
            int c = it * 256 + tid;
            int row = c >> 4, sg = c & 15;
            *(int4*)&Bs[row][sg * 8] =
                *(const int4*)(wt + (long)row * 1152 + tap * 128 + sg * 8);
        }
        __syncthreads();
        #pragma unroll
        for (int ib = 0; ib < 4; ++ib) {
            bf16x8 afr[2], bfr[4];
            #pragma unroll
            for (int mt = 0; mt < 2; ++mt)
                afr[mt] = *(bf16x8*)&As[wr * 32 + mt * 16 + l15][ib * 32 + quad * 8];
            #pragma unroll
            for (int nt = 0; nt < 4; ++nt)
                bfr[nt] = *(bf16x8*)&Bs[wc * 64 + nt * 16 + l15][ib * 32 + quad * 8];
            #pragma unroll
            for (int mt = 0; mt < 2; ++mt)
                #pragma unroll
                for (int nt = 0; nt < 4; ++nt)
                    acc[mt][nt] = __builtin_amdgcn_mfma_f32_16x16x32_bf16(
                        afr[mt], bfr[nt], acc[mt][nt], 0, 0, 0);
        }
    }
    __syncthreads();   // As/Bs dead; o_s aliases them
    #pragma unroll
    for (int mt = 0; mt < 2; ++mt)
        #pragma unroll
        for (int r = 0; r < 4; ++r) {
            int wo = wr * 32 + mt * 16 + quad * 4 + r;
            #pragma unroll
            for (int nt = 0; nt < 4; ++nt) {
                int col = wc * 64 + nt * 16 + l15;
                o_s[wo][col] = acc[mt][nt][r];
            }
        }
    __syncthreads();

    {
        int r = tid >> 2, qq = tid & 3;
        float s = 0.f, ss = 0.f;
        #pragma unroll
        for (int j = 0; j < 32; ++j) {
            float v = o_s[r][qq * 32 + j];
            s += v; ss += v * v;
        }
        s  += __shfl_xor(s, 1, 64);  ss += __shfl_xor(ss, 1, 64);
        s  += __shfl_xor(s, 2, 64);  ss += __shfl_xor(ss, 2, 64);
        float mu = s * (1.0f / DIM);
        float var = fmaxf(ss * (1.0f / DIM) - mu * mu, 0.0f);
        float rstd = rsqrtf(var + EPS_LN);
        long outb = ((long)b * NPOS + ho * WOq) * DIM;
        float* xr = out_x + outb + (long)r * DIM + qq * 32;
        #pragma unroll
        for (int j = 0; j < 32; ++j) {
            int c = qq * 32 + j;
            xr[j] = (o_s[r][c] - mu) * rstd * ln_g[c] + ln_b[c];
        }
    }
}

// ---------------------------------------------------------------------------
// kv dual MFMA GEMM. K and V both written as bf16.
__global__ __launch_bounds__(256) void kv_mfma_kernel(
        const unsigned short* __restrict__ x_bf,
        const unsigned short* __restrict__ xln_bf,
        const unsigned short* __restrict__ kwt,
        const unsigned short* __restrict__ vwt,
        unsigned short* __restrict__ k_bf, unsigned short* __restrict__ v_bf) {
    __shared__ unsigned short Ak[64][40], Av[64][40];
    __shared__ unsigned short Bk[128][40], Bv[128][40];
    int tid = threadIdx.x;
    int wv = tid >> 6, lane = tid & 63;
    int quad = lane >> 4, l15 = lane & 15;
    int wr = wv >> 1, wc = wv & 1;
    long tokBase = (long)blockIdx.x * 64;

    f32x4 acck[2][4], accv[2][4];
    #pragma unroll
    for (int mt = 0; mt < 2; ++mt)
        #pragma unroll
        for (int nt = 0; nt < 4; ++nt) {
            acck[mt][nt] = (f32x4){0.f, 0.f, 0.f, 0.f};
            accv[mt][nt] = (f32x4){0.f, 0.f, 0.f, 0.f};
        }

    int m = tid >> 2, seg = tid & 3;
    #pragma unroll
    for (int ib = 0; ib < 4; ++ib) {
        __syncthreads();
        *(int4*)&Ak[m][seg * 8] = *(const int4*)(xln_bf + (tokBase + m) * DIM + ib * 32 + seg * 8);
        *(int4*)&Av[m][seg * 8] = *(const int4*)(x_bf   + (tokBase + m) * DIM + ib * 32 + seg * 8);
        #pragma unroll
        for (int r2 = 0; r2 < 2; ++r2) {
            int lin = r2 * 256 + tid;
            int n = lin >> 2, sg = lin & 3;
            *(int4*)&Bk[n][sg * 8] = *(const int4*)(kwt + (long)n * DIM + ib * 32 + sg * 8);
            *(int4*)&Bv[n][sg * 8] = *(const int4*)(vwt + (long)n * DIM + ib * 32 + sg * 8);
        }
        __syncthreads();
        bf16x8 ak[2], av2[2], bk[4], bv[4];
        #pragma unroll
        for (int mt = 0; mt < 2; ++mt) {
            ak[mt]  = *(bf16x8*)&Ak[wr * 32 + mt * 16 + l15][quad * 8];
            av2[mt] = *(bf16x8*)&Av[wr * 32 + mt * 16 + l15][quad * 8];
        }
        #pragma unroll
        for (int nt = 0; nt < 4; ++nt) {
            bk[nt] = *(bf16x8*)&Bk[wc * 64 + nt * 16 + l15][quad * 8];
            bv[nt] = *(bf16x8*)&Bv[wc * 64 + nt * 16 + l15][quad * 8];
        }
        #pragma unroll
        for (int mt = 0; mt < 2; ++mt)
            #pragma unroll
            for (int nt = 0; nt < 4; ++nt) {
                acck[mt][nt] = __builtin_amdgcn_mfma_f32_16x16x32_bf16(ak[mt],  bk[nt], acck[mt][nt], 0, 0, 0);
                accv[mt][nt] = __builtin_amdgcn_mfma_f32_16x16x32_bf16(av2[mt], bv[nt], accv[mt][nt], 0, 0, 0);
            }
    }
    #pragma unroll
    for (int mt = 0; mt < 2; ++mt)
        #pragma unroll
        for (int r = 0; r < 4; ++r) {
            long tok = tokBase + wr * 32 + mt * 16 + quad * 4 + r;
            int b = (int)(tok >> 14);
            int pix = (int)(tok & 16383);
            int ih = pix >> 7, iw = pix & 127;
            int g = (ih & 1) * 2 + (iw & 1);
            int pos = (ih >> 1) * WOq + (iw >> 1);
            long base = ((long)(b * 4 + g) * NPOS + pos) * DIM;
            #pragma unroll
            for (int nt = 0; nt < 4; ++nt) {
                int col = wc * 64 + nt * 16 + l15;
                k_bf[base + col] = f2bf(acck[mt][nt][r]);
                v_bf[base + col] = f2bf(accv[mt][nt][r]);
            }
        }
}

// ---------------------------------------------------------------------------
// q = LN(x_out)@q_w via MFMA, output bf16. Also zeroes col_sums.
__global__ __launch_bounds__(256) void q_mfma_kernel(
        const float* __restrict__ x_out,
        const unsigned short* __restrict__ qwt,
        const float* __restrict__ ln_g, const float* __restrict__ ln_b,
        unsigned short* __restrict__ q,
        float* __restrict__ col_sums) {
    __shared__ unsigned short sxbf[64][136];
    int tid = threadIdx.x;
    long base = (long)blockIdx.x * 64;

    int zi = blockIdx.x * 256 + tid;
    if (zi < BN * NPOS) col_sums[zi] = 0.0f;

    {
        int r = tid >> 2, qq = tid & 3;
        const float* xr = x_out + (base + r) * DIM + qq * 32;
        float vv[32];
        float s = 0.f, ss = 0.f;
        #pragma unroll
        for (int j = 0; j < 8; ++j) {
            float4 v4 = *(const float4*)(xr + j * 4);
            vv[j * 4 + 0] = v4.x; vv[j * 4 + 1] = v4.y;
            vv[j * 4 + 2] = v4.z; vv[j * 4 + 3] = v4.w;
            s += v4.x + v4.y + v4.z + v4.w;
            ss += v4.x * v4.x + v4.y * v4.y + v4.z * v4.z + v4.w * v4.w;
        }
        s  += __shfl_xor(s, 1, 64);  ss += __shfl_xor(ss, 1, 64);
        s  += __shfl_xor(s, 2, 64);  ss += __shfl_xor(ss, 2, 64);
        float mu = s * (1.0f / DIM);
        float var = fmaxf(ss * (1.0f / DIM) - mu * mu, 0.0f);
        float rstd = rsqrtf(var + EPS_LN);
        #pragma unroll
        for (int j = 0; j < 32; ++j) {
            int c = qq * 32 + j;
            sxbf[r][c] = f2bf((vv[j] - mu) * rstd * ln_g[c] + ln_b[c]);
        }
    }
    __syncthreads();

    int wv = tid >> 6, lane = tid & 63;
    int quad = lane >> 4, l15 = lane & 15;
    f32x4 acc[4][2];
    #pragma unroll
    for (int mt = 0; mt < 4; ++mt)
        #pragma unroll
        for (int nt = 0; nt < 2; ++nt) acc[mt][nt] = (f32x4){0.f, 0.f, 0.f, 0.f};

    #pragma unroll
    for (int kb = 0; kb < 4; ++kb) {
        bf16x8 afr[4], bfr[2];
        #pragma unroll
        for (int mt = 0; mt < 4; ++mt)
            afr[mt] = *(bf16x8*)&sxbf[mt * 16 + l15][kb * 32 + quad * 8];
        #pragma unroll
        for (int nt = 0; nt < 2; ++nt) {
            int n = wv * 32 + nt * 16 + l15;
            bfr[nt] = *(const bf16x8*)(qwt + (long)n * DIM + kb * 32 + quad * 8);
        }
        #pragma unroll
        for (int mt = 0; mt < 4; ++mt)
            #pragma unroll
            for (int nt = 0; nt < 2; ++nt)
                acc[mt][nt] = __builtin_amdgcn_mfma_f32_16x16x32_bf16(
                    afr[mt], bfr[nt], acc[mt][nt], 0, 0, 0);
    }
    #pragma unroll
    for (int mt = 0; mt < 4; ++mt)
        #pragma unroll
        for (int r = 0; r < 4; ++r) {
            long tok = base + mt * 16 + quad * 4 + r;
            #pragma unroll
            for (int nt = 0; nt < 2; ++nt) {
                int col = wv * 32 + nt * 16 + l15;
                q[tok * DIM + col] = f2bf(acc[mt][nt][r]);
            }
        }
}

// ---------------------------------------------------------------------------
// attn (MFMA), round-6 proven.
__global__ __launch_bounds__(256) void attn_mfma_kernel(
        const unsigned short* __restrict__ k_bf,
        const unsigned short* __restrict__ q_bf,
        const float* __restrict__ rpb,
        const float* __restrict__ tau,
        float* __restrict__ attn_out,
        float* __restrict__ col_sums) {
    __shared__ __align__(16) char smem[69632];
    __shared__ float colacc[192];
    unsigned short (*Ks)[136] = (unsigned short(*)[136])smem;            // 17408 B
    unsigned short (*Qs)[136] = (unsigned short(*)[136])(smem + 17408);  // 52224 B
    float (*S)[193]           = (float(*)[193])smem;                     // 49408 B aliased

    int tid = threadIdx.x;
    int bid = blockIdx.x;
    int h = bid & 63, g = (bid >> 6) & 3, b = bid >> 8;
    int r0 = min(max(h, 1), HOq - 2) - 1;

    long kbase = ((long)(b * 4 + g) * NPOS + h * 64) * DIM;
    long qbase = ((long)b * NPOS + r0 * 64) * DIM;

    if (tid < 192) colacc[tid] = 0.f;

    #pragma unroll
    for (int it = 0; it < 4; ++it) {
        int lin = it * 256 + tid;
        int row = lin >> 4, sg = lin & 15;
        *(int4*)&Ks[row][sg * 8] = *(const int4*)(k_bf + kbase + (long)row * DIM + sg * 8);
    }
    #pragma unroll
    for (int it = 0; it < 12; ++it) {
        int lin = it * 256 + tid;
        int row = lin >> 4, sg = lin & 15;
        *(int4*)&Qs[row][sg * 8] = *(const int4*)(q_bf + qbase + (long)row * DIM + sg * 8);
    }
    __syncthreads();

    int wv = tid >> 6, lane = tid & 63;
    int quad = lane >> 4, l15 = lane & 15;
    f32x4 acc[4][3];
    #pragma unroll
    for (int mt = 0; mt < 4; ++mt)
        #pragma unroll
        for (int nt = 0; nt < 3; ++nt) acc[mt][nt] = (f32x4){0.f, 0.f, 0.f, 0.f};

    #pragma unroll
    for (int kb = 0; kb < 4; ++kb) {
        bf16x8 afr[4], bfr[3];
        #pragma unroll
        for (int mt = 0; mt < 4; ++mt)
            afr[mt] = *(bf16x8*)&Ks[mt * 16 + l15][kb * 32 + quad * 8];
        #pragma unroll
        for (int nt = 0; nt < 3; ++nt)
            bfr[nt] = *(bf16x8*)&Qs[wv * 48 + nt * 16 + l15][kb * 32 + quad * 8];
        #pragma unroll
        for (int mt = 0; mt < 4; ++mt)
            #pragma unroll
            for (int nt = 0; nt < 3; ++nt)
                acc[mt][nt] = __builtin_amdgcn_mfma_f32_16x16x32_bf16(
                    afr[mt], bfr[nt], acc[mt][nt], 0, 0, 0);
    }
    __syncthreads();
    #pragma unroll
    for (int mt = 0; mt < 4; ++mt)
        #pragma unroll
        for (int nt = 0; nt < 3; ++nt)
            #pragma unroll
            for (int r = 0; r < 4; ++r)
                S[mt * 16 + quad * 4 + r][wv * 48 + nt * 16 + l15] = acc[mt][nt][r];
    __syncthreads();

    if (tid < 64) {
        int w = tid;
        int cw = min(max(w, 1), WOq - 2);
        float scale = expf(tau[0]);
        float l[9];
        #pragma unroll
        for (int t = 0; t < 9; ++t) {
            int j = (t / 3) * 64 + cw - 1 + (t % 3);
            l[t] = (S[w][j] + rpb[g * 9 + t]) * scale;
        }
        float m = l[0];
        #pragma unroll
        for (int t = 1; t < 9; ++t) m = fmaxf(m, l[t]);
        float e[9], s = 0.f;
        #pragma unroll
        for (int t = 0; t < 9; ++t) { e[t] = __expf(l[t] - m); s += e[t]; }
        float inv = 1.0f / s;
        long cell = (long)(b * 4 + g) * NPOS + h * 64 + w;
        #pragma unroll
        for (int t = 0; t < 9; ++t) {
            float a = e[t] * inv + EPS_A;
            int j = (t / 3) * 64 + cw - 1 + (t % 3);
            attn_out[cell * 9 + t] = a;
            atomicAdd(&colacc[j], a);
        }
    }
    __syncthreads();
    if (tid < 192) atomicAdd(&col_sums[b * NPOS + r0 * 64 + tid], colacc[tid]);
}

// ---------------------------------------------------------------------------
// acol_upd (round-6 proven structure): 16384 blocks x 128 threads, bf16 V.
__global__ void acol_upd_kernel(const float* __restrict__ attn_out,
                                const float* __restrict__ col_sums,
                                const unsigned short* __restrict__ v_bf,
                                float* __restrict__ acol_out,
                                float* __restrict__ x_out) {
    __shared__ float sA[36];
    int tid = threadIdx.x;
    int row = blockIdx.x;
    int b = row >> 12, pos = row & 4095;
    int h = pos >> 6, w = pos & 63;

    if (tid < 36) {
        int g = tid / 9, t = tid % 9;
        long ci = ((long)(b * 4 + g) * NPOS + pos) * 9 + t;
        float a = attn_out[ci];
        float cs = col_sums[b * NPOS + nb_index(h, w, t)];
        float A = a / (cs + 1e-8f);
        sA[tid] = A;
        acol_out[ci] = A;
    }
    __syncthreads();

    int nn[9];
    #pragma unroll
    for (int t = 0; t < 9; ++t) nn[t] = nb_index(h, w, t);

    float acc = 0.f;
    #pragma unroll
    for (int g = 0; g < 4; ++g) {
        const unsigned short* vb = v_bf + (long)(b * 4 + g) * NPOS * DIM;
        #pragma unroll
        for (int t = 0; t < 9; ++t) {
            acc += sA[g * 9 + t] * bf2f(vb[(long)nn[t] * DIM + tid]);
        }
    }
    x_out[(long)row * DIM + tid] += acc;
}

// ---------------------------------------------------------------------------
// Fused MFMA MLP v2: 32 tokens/block, grid 512 -> 2 blocks/CU so the serial
// stage->GEMM1->gelu->GEMM2->LN ladder of one block overlaps the other's.
// Same fragment conventions as proven kernels; LDS 25.6 KB.
__global__ __launch_bounds__(256) void mlp_mfma_kernel(
        float* __restrict__ x_out,
        const unsigned short* __restrict__ w1t,  // [256][128]
        const unsigned short* __restrict__ w2t,  // [128][256]
        const float* __restrict__ b1, const float* __restrict__ b2,
        const float* __restrict__ ln_g, const float* __restrict__ ln_b) {
    __shared__ __align__(16) char smem[25600];
    unsigned short (*sxbf)[136] = (unsigned short(*)[136])smem;           // 8704 B
    unsigned short (*h_s)[264]  = (unsigned short(*)[264])(smem + 8704);  // 16896 B
    float (*o_s)[132]           = (float(*)[132])smem;                    // aliased, 16896 B

    int tid = threadIdx.x;
    long base = (long)blockIdx.x * 32;
    int wv = tid >> 6, lane = tid & 63;
    int quad = lane >> 4, l15 = lane & 15;

    // stage x -> bf16: 8 threads per row, 16 cols each (32 rows)
    {
        int r = tid >> 3, seg = tid & 7;
        const float* xr = x_out + (base + r) * DIM + seg * 16;
        #pragma unroll
        for (int j = 0; j < 2; ++j) {
            float4 a = *(const float4*)(xr + j * 8);
            float4 c = *(const float4*)(xr + j * 8 + 4);
            unsigned short u[8] = {f2bf(a.x), f2bf(a.y), f2bf(a.z), f2bf(a.w),
                                   f2bf(c.x), f2bf(c.y), f2bf(c.z), f2bf(c.w)};
            *(int4*)&sxbf[r][seg * 16 + j * 8] = *(int4*)u;
        }
    }
    __syncthreads();

    // GEMM1: M=32, N=256 (wave wv -> cols wv*64..+64), K=128
    f32x4 acc1[2][4];
    #pragma unroll
    for (int mt = 0; mt < 2; ++mt)
        #pragma unroll
        for (int nt = 0; nt < 4; ++nt) acc1[mt][nt] = (f32x4){0.f, 0.f, 0.f, 0.f};
    #pragma unroll
    for (int kb = 0; kb < 4; ++kb) {
        bf16x8 afr[2], bfr[4];
        #pragma unroll
        for (int mt = 0; mt < 2; ++mt)
            afr[mt] = *(bf16x8*)&sxbf[mt * 16 + l15][kb * 32 + quad * 8];
        #pragma unroll
        for (int nt = 0; nt < 4; ++nt) {
            int n = wv * 64 + nt * 16 + l15;
            bfr[nt] = *(const bf16x8*)(w1t + (long)n * DIM + kb * 32 + quad * 8);
        }
        #pragma unroll
        for (int mt = 0; mt < 2; ++mt)
            #pragma unroll
            for (int nt = 0; nt < 4; ++nt)
                acc1[mt][nt] = __builtin_amdgcn_mfma_f32_16x16x32_bf16(
                    afr[mt], bfr[nt], acc1[mt][nt], 0, 0, 0);
    }
    // bias + gelu -> h_s (bf16)
    #pragma unroll
    for (int nt = 0; nt < 4; ++nt) {
        int col = wv * 64 + nt * 16 + l15;
        float bj = b1[col];
        #pragma unroll
        for (int mt = 0; mt < 2; ++mt)
            #pragma unroll
            for (int r = 0; r < 4; ++r) {
                int row = mt * 16 + quad * 4 + r;
                float hv = acc1[mt][nt][r] + bj;
                hv = 0.5f * hv * (1.0f + erff(hv * 0.70710678118654752f));
                h_s[row][col] = f2bf(hv);
            }
    }
    __syncthreads();

    // GEMM2: M=32, N=128 (wave wv -> cols wv*32..+32), K=256
    f32x4 acc2[2][2];
    #pragma unroll
    for (int mt = 0; mt < 2; ++mt)
        #pragma unroll
        for (int nt = 0; nt < 2; ++nt) acc2[mt][nt] = (f32x4){0.f, 0.f, 0.f, 0.f};
    #pragma unroll
    for (int kb = 0; kb < 8; ++kb) {
        bf16x8 afr[2], bfr[2];
        #pragma unroll
        for (int mt = 0; mt < 2; ++mt)
            afr[mt] = *(bf16x8*)&h_s[mt * 16 + l15][kb * 32 + quad * 8];
        #pragma unroll
        for (int nt = 0; nt < 2; ++nt) {
            int n = wv * 32 + nt * 16 + l15;
            bfr[nt] = *(const bf16x8*)(w2t + (long)n * 256 + kb * 32 + quad * 8);
        }
        #pragma unroll
        for (int mt = 0; mt < 2; ++mt)
            #pragma unroll
            for (int nt = 0; nt < 2; ++nt)
                acc2[mt][nt] = __builtin_amdgcn_mfma_f32_16x16x32_bf16(
                    afr[mt], bfr[nt], acc2[mt][nt], 0, 0, 0);
    }
    __syncthreads();   // h_s dead; safe to write aliased o_s

    #pragma unroll
    for (int nt = 0; nt < 2; ++nt) {
        int col = wv * 32 + nt * 16 + l15;
        float bj = b2[col];
        #pragma unroll
        for (int mt = 0; mt < 2; ++mt)
            #pragma unroll
            for (int r = 0; r < 4; ++r)
                o_s[mt * 16 + quad * 4 + r][col] = acc2[mt][nt][r] + bj;
    }
    __syncthreads();

    // LN(o) + residual. 8 threads per row, 16 cols each (32 rows).
    {
        int r = tid >> 3, qq = tid & 7;
        float s = 0.f, ss = 0.f;
        #pragma unroll
        for (int j = 0; j < 16; ++j) {
            float v = o_s[r][qq * 16 + j];
            s += v; ss += v * v;
        }
        s  += __shfl_xor(s, 1, 64);  ss += __shfl_xor(ss, 1, 64);
        s  += __shfl_xor(s, 2, 64);  ss += __shfl_xor(ss, 2, 64);
        s  += __shfl_xor(s, 4, 64);  ss += __shfl_xor(ss, 4, 64);
        float mu = s * (1.0f / DIM);
        float var = fmaxf(ss * (1.0f / DIM) - mu * mu, 0.0f);
        float rstd = rsqrtf(var + EPS_LN);
        float* xr = x_out + (base + r) * DIM + qq * 16;
        #pragma unroll
        for (int j = 0; j < 16; ++j) {
            int c = qq * 16 + j;
            xr[j] = xr[j] + (o_s[r][c] - mu) * rstd * ln_g[c] + ln_b[c];
        }
    }
}

// ---------------------------------------------------------------------------
extern "C" void kernel_launch(void* const* d_in, const int* in_sizes, int n_in,
                              void* d_out, int out_size, void* d_ws, size_t ws_size,
                              hipStream_t stream) {
    const float* x        = (const float*)d_in[0];
    const float* conv_w   = (const float*)d_in[1];
    const float* q_w      = (const float*)d_in[2];
    const float* k_w      = (const float*)d_in[3];
    const float* v_w      = (const float*)d_in[4];
    const float* mlp_w1   = (const float*)d_in[5];
    const float* mlp_b1   = (const float*)d_in[6];
    const float* mlp_w2   = (const float*)d_in[7];
    const float* mlp_b2   = (const float*)d_in[8];
    const float* ln_in_g  = (const float*)d_in[9];
    const float* ln_in_b  = (const float*)d_in[10];
    const float* ln_out_g = (const float*)d_in[11];
    const float* ln_out_b = (const float*)d_in[12];
    const float* tau      = (const float*)d_in[13];
    const float* rpb      = (const float*)d_in[14];

    float* out_x    = (float*)d_out;
    float* out_attn = out_x + (long)BN * NPOS * DIM;
    float* out_acol = out_attn + (long)BN * 4 * NPOS * 9;

    char* ws = (char*)d_ws;
    unsigned short* k_bf = (unsigned short*)ws; ws += (long)BN * 4 * NPOS * DIM * 4;  // slot kept f32-sized
    unsigned short* v_bf = (unsigned short*)ws; ws += (long)BN * 4 * NPOS * DIM * 4;  // slot kept f32-sized
    unsigned short* x_bf = (unsigned short*)ws;
    unsigned short* q_bf = (unsigned short*)ws;  // q aliases x_bf (setup-only)
    ws += (long)BN * NTOK * DIM * 2;
    unsigned short* xln_bf = (unsigned short*)ws; ws += (long)BN * NTOK * DIM * 2;
    unsigned short* wt_conv = (unsigned short*)ws; ws += 1152L * DIM * 2;
    unsigned short* kwt = (unsigned short*)ws;     ws += (long)DIM * DIM * 2;
    unsigned short* vwt = (unsigned short*)ws;     ws += (long)DIM * DIM * 2;
    unsigned short* qwt = (unsigned short*)ws;     ws += (long)DIM * DIM * 2;
    unsigned short* w1t = (unsigned short*)ws;     ws += 256L * DIM * 2;
    unsigned short* w2t = (unsigned short*)ws;     ws += 256L * DIM * 2;
    float* col_sums = (float*)ws;       ws += (long)BN * NPOS * 4;

    prep_ln_kernel<<<16384, 256, 0, stream>>>(x, ln_in_g, ln_in_b, x_bf, xln_bf);
    wt_prep_kernel<<<128, 128, 0, stream>>>(conv_w, k_w, v_w, q_w, mlp_w1, mlp_w2,
                                            wt_conv, kwt, vwt, qwt, w1t, w2t);

    kv_mfma_kernel<<<1024, 256, 0, stream>>>(x_bf, xln_bf, kwt, vwt, k_bf, v_bf);
    conv_mfma_kernel<<<256, 256, 0, stream>>>(x_bf, wt_conv, ln_out_g, ln_out_b, out_x);

    for (int it = 0; it < 3; ++it) {
        q_mfma_kernel<<<256, 256, 0, stream>>>(out_x, qwt, ln_out_g, ln_out_b, q_bf, col_sums);
        attn_mfma_kernel<<<1024, 256, 0, stream>>>(k_bf, q_bf, rpb, tau, out_attn, col_sums);
        acol_upd_kernel<<<16384, 128, 0, stream>>>(out_attn, col_sums, v_bf, out_acol, out_x);
        mlp_mfma_kernel<<<512, 256, 0, stream>>>(out_x, w1t, w2t, mlp_b1, mlp_b2,
                                                 ln_out_g, ln_out_b);
    }
}